// Round 1
// baseline (436.402 us; speedup 1.0000x reference)
//
#include <hip/hip_runtime.h>
#include <hip/hip_bf16.h>

#define B_ 2
#define SQ_ 2048
#define SKV_ 2048
#define D_ 1024
#define H_ 16
#define HD_ 64

typedef unsigned short u16;
typedef float f32x4 __attribute__((ext_vector_type(4)));
typedef short s16x8 __attribute__((ext_vector_type(8)));

__device__ __forceinline__ u16 f2bf(float f) {
  union { float f; unsigned u; } v; v.f = f;
  return (u16)((v.u + 0x7FFFu + ((v.u >> 16) & 1u)) >> 16);
}
__device__ __forceinline__ float bf2f(u16 h) {
  union { unsigned u; float f; } v; v.u = ((unsigned)h) << 16;
  return v.f;
}
__device__ __forceinline__ f32x4 mfma16(s16x8 a, s16x8 b, f32x4 c) {
  return __builtin_amdgcn_mfma_f32_16x16x32_bf16(a, b, c, 0, 0, 0);
}

// ---------------- cast fp32 -> bf16 ----------------
__global__ __launch_bounds__(256) void cast_kernel(const float* __restrict__ in,
                                                   u16* __restrict__ out, int n) {
  int i = (blockIdx.x * 256 + threadIdx.x) * 4;
  if (i < n) {
    float4 f = *(const float4*)(in + i);
    ushort4 o;
    o.x = f2bf(f.x); o.y = f2bf(f.y); o.z = f2bf(f.z); o.w = f2bf(f.w);
    *(ushort4*)(out + i) = o;
  }
}

// ---------------- transpose + cast: in fp32 (R x C) -> out bf16 (C x R) ----------------
__global__ __launch_bounds__(256) void transpose_cast(const float* __restrict__ in,
                                                      u16* __restrict__ out, int R, int C) {
  __shared__ u16 tile[32][33];
  int c0 = blockIdx.x * 32, r0 = blockIdx.y * 32;
#pragma unroll
  for (int i = 0; i < 4; i++) {
    int r = r0 + threadIdx.y + i * 8;
    int c = c0 + threadIdx.x;
    tile[threadIdx.y + i * 8][threadIdx.x] = f2bf(in[(size_t)r * C + c]);
  }
  __syncthreads();
#pragma unroll
  for (int i = 0; i < 4; i++) {
    int rr = c0 + threadIdx.y + i * 8;  // out row = original col
    int cc = r0 + threadIdx.x;
    out[(size_t)rr * R + cc] = tile[threadIdx.x][threadIdx.y + i * 8];
  }
}

// ---------------- GEMM: C(MxN) = A(MxK) * BT(NxK)^T, bf16 in, fp32 acc ----------------
template <bool OUT_BF16>
__global__ __launch_bounds__(256) void gemm_abt(const u16* __restrict__ A,
                                                const u16* __restrict__ BT,
                                                void* __restrict__ Cout,
                                                int M, int N, int K) {
  __shared__ __attribute__((aligned(16))) u16 As[64][40];
  __shared__ __attribute__((aligned(16))) u16 Bs[64][40];
  int m0 = blockIdx.y * 64, n0 = blockIdx.x * 64;
  int t = threadIdx.x;
  int wave = t >> 6, lane = t & 63;
  int l16 = lane & 15, quad = lane >> 4;
  int mw = (wave >> 1) * 32, nw = (wave & 1) * 32;
  int srow = t >> 2, schunk = (t & 3) * 8;

  f32x4 acc[2][2] = {};

  for (int kt = 0; kt < K; kt += 32) {
    uint4 av = *(const uint4*)(A + (size_t)(m0 + srow) * K + kt + schunk);
    uint4 bv = *(const uint4*)(BT + (size_t)(n0 + srow) * K + kt + schunk);
    __syncthreads();  // previous iter's LDS reads complete
    *(uint4*)&As[srow][schunk] = av;
    *(uint4*)&Bs[srow][schunk] = bv;
    __syncthreads();
    s16x8 af[2], bf[2];
#pragma unroll
    for (int i = 0; i < 2; i++) {
      af[i] = *(const s16x8*)&As[mw + i * 16 + l16][quad * 8];
      bf[i] = *(const s16x8*)&Bs[nw + i * 16 + l16][quad * 8];
    }
#pragma unroll
    for (int mi = 0; mi < 2; mi++)
#pragma unroll
      for (int ni = 0; ni < 2; ni++)
        acc[mi][ni] = mfma16(af[mi], bf[ni], acc[mi][ni]);
  }

#pragma unroll
  for (int mi = 0; mi < 2; mi++)
#pragma unroll
    for (int ni = 0; ni < 2; ni++) {
      int col = n0 + nw + ni * 16 + l16;
#pragma unroll
      for (int r = 0; r < 4; r++) {
        int row = m0 + mw + mi * 16 + quad * 4 + r;
        float v = acc[mi][ni][r];
        if (OUT_BF16)
          ((u16*)Cout)[(size_t)row * N + col] = f2bf(v);
        else
          ((float*)Cout)[(size_t)row * N + col] = v;
      }
    }
}

// ---------------- LayerNorm of v + transpose into vt[b,h,d,s] ----------------
__global__ __launch_bounds__(256) void ln_vt_kernel(const u16* __restrict__ kvh,  // (B*SKV) x 2048
                                                    const float* __restrict__ gamma,
                                                    const float* __restrict__ beta,
                                                    u16* __restrict__ vt) {  // (B*H*HD) x SKV
  __shared__ __attribute__((aligned(16))) u16 tile[64][72];  // [d][s]
  int bid = blockIdx.x;
  int stile = bid & 31;        // SKV/64 = 32
  int h = (bid >> 5) & 15;
  int b = bid >> 9;
  int wave = threadIdx.x >> 6, lane = threadIdx.x & 63;
  float g = gamma[lane], be = beta[lane];
#pragma unroll 4
  for (int i = 0; i < 16; i++) {
    int s = stile * 64 + wave * 16 + i;
    float x = bf2f(kvh[(size_t)(b * SKV_ + s) * 2048 + 1024 + h * 64 + lane]);
    float sum = x;
#pragma unroll
    for (int off = 32; off; off >>= 1) sum += __shfl_xor(sum, off, 64);
    float mu = sum * (1.0f / 64.0f);
    float dx = x - mu;
    float s2 = dx * dx;
#pragma unroll
    for (int off = 32; off; off >>= 1) s2 += __shfl_xor(s2, off, 64);
    float inv = rsqrtf(s2 * (1.0f / 64.0f) + 1e-5f);
    tile[lane][wave * 16 + i] = f2bf(dx * inv * g + be);
  }
  __syncthreads();
  int d = threadIdx.x >> 2, sc = (threadIdx.x & 3) * 16;
  size_t orow = ((size_t)(b * H_ + h) * 64 + d) * SKV_ + stile * 64 + sc;
  uint4 v0 = *(const uint4*)&tile[d][sc];
  uint4 v1 = *(const uint4*)&tile[d][sc + 8];
  *(uint4*)(vt + orow) = v0;
  *(uint4*)(vt + orow + 8) = v1;
}

// ---------------- attention: S = qh k^T /8; P = sigmoid(S-8)*causal; O = P V ----------------
__global__ __launch_bounds__(256) void attn_kernel(const u16* __restrict__ qh,   // (B*SQ) x D
                                                   const u16* __restrict__ kvh,  // (B*SKV) x 2D
                                                   const u16* __restrict__ vt,   // (B*H*HD) x SKV
                                                   float* __restrict__ out0,
                                                   u16* __restrict__ atv_bf) {
  int qtile = blockIdx.x, h = blockIdx.y, b = blockIdx.z;
  int wave = threadIdx.x >> 6, lane = threadIdx.x & 63;
  int l16 = lane & 15, quad = lane >> 4;
  __shared__ __attribute__((aligned(16))) u16 plds[4][16][72];

  int q0 = qtile * 64;
  size_t qrow_g = (size_t)(b * SQ_ + q0 + wave * 16 + l16);
  s16x8 qf[2];
  qf[0] = *(const s16x8*)(qh + qrow_g * D_ + h * 64 + quad * 8);
  qf[1] = *(const s16x8*)(qh + qrow_g * D_ + h * 64 + 32 + quad * 8);

  f32x4 oacc[4] = {};

  int ktiles = qtile + 1;
  for (int kt = 0; kt < ktiles; kt++) {
    int kk0 = kt * 64;
    f32x4 sacc[4] = {};
#pragma unroll
    for (int ni = 0; ni < 4; ni++) {
      size_t krow = (size_t)(b * SKV_ + kk0 + ni * 16 + l16) * 2048 + h * 64;
      s16x8 kf0 = *(const s16x8*)(kvh + krow + quad * 8);
      s16x8 kf1 = *(const s16x8*)(kvh + krow + 32 + quad * 8);
      sacc[ni] = mfma16(qf[0], kf0, sacc[ni]);
      sacc[ni] = mfma16(qf[1], kf1, sacc[ni]);
    }
#pragma unroll
    for (int ni = 0; ni < 4; ni++) {
#pragma unroll
      for (int r = 0; r < 4; r++) {
        int qi = q0 + wave * 16 + quad * 4 + r;
        int kj = kk0 + ni * 16 + l16;
        float sval = sacc[ni][r] * 0.125f - 8.0f;
        float pv = (kj <= qi) ? (1.0f / (1.0f + __expf(-sval))) : 0.0f;
        plds[wave][quad * 4 + r][ni * 16 + l16] = f2bf(pv);
      }
    }
    __syncthreads();
#pragma unroll
    for (int ks = 0; ks < 2; ks++) {
      s16x8 pf = *(const s16x8*)&plds[wave][l16][ks * 32 + quad * 8];
#pragma unroll
      for (int d2 = 0; d2 < 4; d2++) {
        s16x8 vf = *(const s16x8*)(vt + ((size_t)((b * H_ + h) * 64 + d2 * 16 + l16)) * SKV_ +
                                   kk0 + ks * 32 + quad * 8);
        oacc[d2] = mfma16(pf, vf, oacc[d2]);
      }
    }
    __syncthreads();
  }

#pragma unroll
  for (int d2 = 0; d2 < 4; d2++) {
#pragma unroll
    for (int r = 0; r < 4; r++) {
      int qi = q0 + wave * 16 + quad * 4 + r;
      int dd = h * 64 + d2 * 16 + l16;
      size_t idx = (size_t)(b * SQ_ + qi) * D_ + dd;
      float v = oacc[d2][r];
      out0[idx] = v;
      atv_bf[idx] = f2bf(v);
    }
  }
}

extern "C" void kernel_launch(void* const* d_in, const int* in_sizes, int n_in,
                              void* d_out, int out_size, void* d_ws, size_t ws_size,
                              hipStream_t stream) {
  const float* q      = (const float*)d_in[0];
  const float* kv     = (const float*)d_in[1];
  const float* Wq     = (const float*)d_in[2];
  const float* Wkv    = (const float*)d_in[3];
  const float* vgamma = (const float*)d_in[4];
  const float* vbeta  = (const float*)d_in[5];
  const float* Wproj  = (const float*)d_in[6];
  float* out0 = (float*)d_out;
  float* out1 = out0 + (size_t)B_ * SQ_ * D_;

  char* p = (char*)d_ws;
  u16* q_bf  = (u16*)p; p += (size_t)B_ * SQ_ * D_ * 2;        // 8 MB
  u16* kv_bf = (u16*)p; p += (size_t)B_ * SKV_ * D_ * 2;       // 8 MB
  u16* WqT   = (u16*)p; p += (size_t)D_ * D_ * 2;              // 2 MB
  u16* WkvT  = (u16*)p; p += (size_t)2 * D_ * D_ * 2;          // 4 MB
  u16* WprT  = (u16*)p; p += (size_t)D_ * D_ * 2;              // 2 MB
  u16* qh    = (u16*)p; p += (size_t)B_ * SQ_ * D_ * 2;        // 8 MB
  u16* kvh   = (u16*)p; p += (size_t)B_ * SKV_ * 2 * D_ * 2;   // 16 MB
  u16* vt    = (u16*)p; p += (size_t)B_ * H_ * HD_ * SKV_ * 2; // 8 MB
  u16* atv   = (u16*)p; p += (size_t)B_ * SQ_ * D_ * 2;        // 8 MB

  cast_kernel<<<dim3((B_ * SQ_ * D_) / 1024), 256, 0, stream>>>(q, q_bf, B_ * SQ_ * D_);
  cast_kernel<<<dim3((B_ * SKV_ * D_) / 1024), 256, 0, stream>>>(kv, kv_bf, B_ * SKV_ * D_);
  transpose_cast<<<dim3(D_ / 32, D_ / 32), dim3(32, 8), 0, stream>>>(Wq, WqT, D_, D_);
  transpose_cast<<<dim3(2 * D_ / 32, D_ / 32), dim3(32, 8), 0, stream>>>(Wkv, WkvT, D_, 2 * D_);
  transpose_cast<<<dim3(D_ / 32, D_ / 32), dim3(32, 8), 0, stream>>>(Wproj, WprT, D_, D_);

  gemm_abt<true><<<dim3(D_ / 64, (B_ * SQ_) / 64), 256, 0, stream>>>(q_bf, WqT, qh, B_ * SQ_, D_, D_);
  gemm_abt<true><<<dim3((2 * D_) / 64, (B_ * SKV_) / 64), 256, 0, stream>>>(kv_bf, WkvT, kvh, B_ * SKV_, 2 * D_, D_);

  ln_vt_kernel<<<dim3((B_ * H_ * SKV_) / 64), 256, 0, stream>>>(kvh, vgamma, vbeta, vt);

  attn_kernel<<<dim3(SQ_ / 64, H_, B_), 256, 0, stream>>>(qh, kvh, vt, out0, atv);

  gemm_abt<false><<<dim3(D_ / 64, (B_ * SQ_) / 64), 256, 0, stream>>>(atv, WprT, out1, B_ * SQ_, D_, D_);
}

// Round 2
// 255.428 us; speedup vs baseline: 1.7085x; 1.7085x over previous
//
#include <hip/hip_runtime.h>
#include <hip/hip_bf16.h>

#define B_ 2
#define SQ_ 2048
#define SKV_ 2048
#define D_ 1024
#define H_ 16
#define HD_ 64

typedef unsigned short u16;
typedef float f32x4 __attribute__((ext_vector_type(4)));
typedef short s16x8 __attribute__((ext_vector_type(8)));

__device__ __forceinline__ u16 f2bf(float f) {
  union { float f; unsigned u; } v; v.f = f;
  return (u16)((v.u + 0x7FFFu + ((v.u >> 16) & 1u)) >> 16);
}
__device__ __forceinline__ float bf2f(u16 h) {
  union { unsigned u; float f; } v; v.u = ((unsigned)h) << 16;
  return v.f;
}
__device__ __forceinline__ f32x4 mfma16(s16x8 a, s16x8 b, f32x4 c) {
  return __builtin_amdgcn_mfma_f32_16x16x32_bf16(a, b, c, 0, 0, 0);
}

// ---------------- cast fp32 -> bf16 ----------------
__global__ __launch_bounds__(256) void cast_kernel(const float* __restrict__ in,
                                                   u16* __restrict__ out, int n) {
  int i = (blockIdx.x * 256 + threadIdx.x) * 4;
  if (i < n) {
    float4 f = *(const float4*)(in + i);
    ushort4 o;
    o.x = f2bf(f.x); o.y = f2bf(f.y); o.z = f2bf(f.z); o.w = f2bf(f.w);
    *(ushort4*)(out + i) = o;
  }
}

// ---------------- transpose + cast: in fp32 (R x C) -> out bf16 (C x R) ----------------
__global__ __launch_bounds__(256) void transpose_cast(const float* __restrict__ in,
                                                      u16* __restrict__ out, int R, int C) {
  __shared__ u16 tile[32][33];
  int c0 = blockIdx.x * 32, r0 = blockIdx.y * 32;
#pragma unroll
  for (int i = 0; i < 4; i++) {
    int r = r0 + threadIdx.y + i * 8;
    int c = c0 + threadIdx.x;
    tile[threadIdx.y + i * 8][threadIdx.x] = f2bf(in[(size_t)r * C + c]);
  }
  __syncthreads();
#pragma unroll
  for (int i = 0; i < 4; i++) {
    int rr = c0 + threadIdx.y + i * 8;  // out row = original col
    int cc = r0 + threadIdx.x;
    out[(size_t)rr * R + cc] = tile[threadIdx.x][threadIdx.y + i * 8];
  }
}

// ---------------- GEMM: C(MxN) = A(MxK) * BT(NxK)^T, 128x128 tile, bf16 in, fp32 acc ----
template <bool OUT_BF16>
__global__ __launch_bounds__(256) void gemm_abt(const u16* __restrict__ A,
                                                const u16* __restrict__ BT,
                                                void* __restrict__ Cout,
                                                int M, int N, int K) {
  // BK = 32. pad rows to 36 elements (72B stride = 18 banks -> 2-way, free)
  __shared__ __attribute__((aligned(16))) u16 As[128][36];
  __shared__ __attribute__((aligned(16))) u16 Bs[128][36];
  int m0 = blockIdx.y * 128, n0 = blockIdx.x * 128;
  int t = threadIdx.x;
  int w = t >> 6, lane = t & 63;
  int l16 = lane & 15, quad = lane >> 4;
  int mw = (w >> 1) * 64, nw = (w & 1) * 64;
  int srow = t >> 1, scol = (t & 1) * 16;  // 2 threads/row, 32B each

  f32x4 acc[4][4] = {};
  uint4 ar0, ar1, br0, br1;

  const u16* ga_base = A + (size_t)(m0 + srow) * K + scol;
  const u16* gb_base = BT + (size_t)(n0 + srow) * K + scol;

  // prefetch k-slab 0
  ar0 = *(const uint4*)(ga_base); ar1 = *(const uint4*)(ga_base + 8);
  br0 = *(const uint4*)(gb_base); br1 = *(const uint4*)(gb_base + 8);

  for (int kt = 0; kt < K; kt += 32) {
    __syncthreads();  // all waves done reading previous slab
    *(uint4*)&As[srow][scol] = ar0; *(uint4*)&As[srow][scol + 8] = ar1;
    *(uint4*)&Bs[srow][scol] = br0; *(uint4*)&Bs[srow][scol + 8] = br1;
    __syncthreads();
    if (kt + 32 < K) {  // prefetch next slab; overlaps MFMAs below
      ar0 = *(const uint4*)(ga_base + kt + 32); ar1 = *(const uint4*)(ga_base + kt + 40);
      br0 = *(const uint4*)(gb_base + kt + 32); br1 = *(const uint4*)(gb_base + kt + 40);
    }
    s16x8 af[4], bf[4];
#pragma unroll
    for (int i = 0; i < 4; i++) {
      af[i] = *(const s16x8*)&As[mw + i * 16 + l16][quad * 8];
      bf[i] = *(const s16x8*)&Bs[nw + i * 16 + l16][quad * 8];
    }
#pragma unroll
    for (int i = 0; i < 4; i++)
#pragma unroll
      for (int j = 0; j < 4; j++)
        acc[i][j] = mfma16(af[i], bf[j], acc[i][j]);
  }

#pragma unroll
  for (int i = 0; i < 4; i++)
#pragma unroll
    for (int j = 0; j < 4; j++) {
      int col = n0 + nw + j * 16 + l16;
#pragma unroll
      for (int r = 0; r < 4; r++) {
        int row = m0 + mw + i * 16 + quad * 4 + r;
        float v = acc[i][j][r];
        if (OUT_BF16)
          ((u16*)Cout)[(size_t)row * N + col] = f2bf(v);
        else
          ((float*)Cout)[(size_t)row * N + col] = v;
      }
    }
}

// ---------------- LayerNorm of v + transpose into vt[b,h,d,s] ----------------
__global__ __launch_bounds__(256) void ln_vt_kernel(const u16* __restrict__ kvh,  // (B*SKV) x 2048
                                                    const float* __restrict__ gamma,
                                                    const float* __restrict__ beta,
                                                    u16* __restrict__ vt) {  // (B*H*HD) x SKV
  __shared__ __attribute__((aligned(16))) u16 tile[64][72];  // [d][s]
  int bid = blockIdx.x;
  int stile = bid & 31;        // SKV/64 = 32
  int h = (bid >> 5) & 15;
  int b = bid >> 9;
  int wave = threadIdx.x >> 6, lane = threadIdx.x & 63;
  float g = gamma[lane], be = beta[lane];
#pragma unroll 4
  for (int i = 0; i < 16; i++) {
    int s = stile * 64 + wave * 16 + i;
    float x = bf2f(kvh[(size_t)(b * SKV_ + s) * 2048 + 1024 + h * 64 + lane]);
    float sum = x;
#pragma unroll
    for (int off = 32; off; off >>= 1) sum += __shfl_xor(sum, off, 64);
    float mu = sum * (1.0f / 64.0f);
    float dx = x - mu;
    float s2 = dx * dx;
#pragma unroll
    for (int off = 32; off; off >>= 1) s2 += __shfl_xor(s2, off, 64);
    float inv = rsqrtf(s2 * (1.0f / 64.0f) + 1e-5f);
    tile[lane][wave * 16 + i] = f2bf(dx * inv * g + be);
  }
  __syncthreads();
  int d = threadIdx.x >> 2, sc = (threadIdx.x & 3) * 16;
  size_t orow = ((size_t)(b * H_ + h) * 64 + d) * SKV_ + stile * 64 + sc;
  uint4 v0 = *(const uint4*)&tile[d][sc];
  uint4 v1 = *(const uint4*)&tile[d][sc + 8];
  *(uint4*)(vt + orow) = v0;
  *(uint4*)(vt + orow + 8) = v1;
}

// ---------------- attention ----------------
// 128-row Q tiles, 16 tiles total per (b,h). Block handles q-tile pair (p, 15-p)
// -> every block does exactly 34 kt iterations (uniform). Grid = 8*16*2 = 256 blocks.
// K/V tiles staged once per block into LDS (register double-buffered prefetch).
__global__ __launch_bounds__(256) void attn_kernel(const u16* __restrict__ qh,   // (B*SQ) x D
                                                   const u16* __restrict__ kvh,  // (B*SKV) x 2D
                                                   const u16* __restrict__ vt,   // (B*H*HD) x SKV
                                                   float* __restrict__ out0,
                                                   u16* __restrict__ atv_bf) {
  __shared__ __attribute__((aligned(16))) u16 Ks[64][68];      // [k][d] pad->2-way free
  __shared__ __attribute__((aligned(16))) u16 Vs[64][68];      // [d][k]
  __shared__ __attribute__((aligned(16))) u16 Ps[4][32][68];   // per-wave P tiles

  int pair = blockIdx.x;  // 0..7
  int h = blockIdx.y, b = blockIdx.z;
  int t = threadIdx.x;
  int w = t >> 6, lane = t & 63;
  int l16 = lane & 15, quad = lane >> 4;
  int srow = t >> 2;           // 0..63 staging row
  int scol = (t & 3) * 16;     // element offset: 4 threads x 32B per 128B row

  const float C1 = -0.18033688011f;  // -0.125 * log2(e)
  const float C2 = 11.5415603272f;   // 8 * log2(e)

#pragma unroll
  for (int half = 0; half < 2; half++) {
    int qt = half ? (15 - pair) : pair;
    int q0 = qt * 128;
    int nkt = 2 * qt + 2;

    // q fragments: wave owns 32 q-rows (2 sub-tiles of 16)
    s16x8 qf[2][2];
#pragma unroll
    for (int m = 0; m < 2; m++) {
      size_t qrow = (size_t)(b * SQ_ + q0 + w * 32 + m * 16 + l16);
#pragma unroll
      for (int c = 0; c < 2; c++)
        qf[m][c] = *(const s16x8*)(qh + qrow * D_ + h * 64 + c * 32 + quad * 8);
    }

    f32x4 oacc[2][4] = {};

    // prefetch kt = 0
    const u16* gk = kvh + ((size_t)(b * SKV_) + srow) * 2048 + h * 64 + scol;
    const u16* gv = vt + ((size_t)((b * H_ + h) * 64 + srow)) * 2048 + scol;
    uint4 kr0 = *(const uint4*)gk, kr1 = *(const uint4*)(gk + 8);
    uint4 vr0 = *(const uint4*)gv, vr1 = *(const uint4*)(gv + 8);

    for (int kt = 0; kt < nkt; kt++) {
      __syncthreads();  // everyone done with previous K/V tile
      *(uint4*)&Ks[srow][scol] = kr0; *(uint4*)&Ks[srow][scol + 8] = kr1;
      *(uint4*)&Vs[srow][scol] = vr0; *(uint4*)&Vs[srow][scol + 8] = vr1;
      __syncthreads();
      if (kt + 1 < nkt) {  // prefetch next tile; overlaps compute below
        const u16* gk2 = gk + (size_t)(kt + 1) * 64 * 2048;
        const u16* gv2 = gv + (size_t)(kt + 1) * 64;
        kr0 = *(const uint4*)gk2; kr1 = *(const uint4*)(gk2 + 8);
        vr0 = *(const uint4*)gv2; vr1 = *(const uint4*)(gv2 + 8);
      }

      // ---- S = q k^T ----
      f32x4 sacc[2][4] = {};
#pragma unroll
      for (int ni = 0; ni < 4; ni++) {
        s16x8 kf0 = *(const s16x8*)&Ks[ni * 16 + l16][quad * 8];
        s16x8 kf1 = *(const s16x8*)&Ks[ni * 16 + l16][32 + quad * 8];
#pragma unroll
        for (int m = 0; m < 2; m++) {
          sacc[m][ni] = mfma16(qf[m][0], kf0, sacc[m][ni]);
          sacc[m][ni] = mfma16(qf[m][1], kf1, sacc[m][ni]);
        }
      }

      // ---- P = sigmoid(S/8 - 8) * causal, to per-wave LDS ----
      int kk0 = kt * 64;
      bool need_mask = (kt >= 2 * qt);  // only diagonal k-tiles can mask
#pragma unroll
      for (int m = 0; m < 2; m++)
#pragma unroll
        for (int ni = 0; ni < 4; ni++)
#pragma unroll
          for (int r = 0; r < 4; r++) {
            float s = sacc[m][ni][r];
            float e = __builtin_amdgcn_exp2f(s * C1 + C2);  // e^{-(s/8-8)}
            float p = __builtin_amdgcn_rcpf(1.0f + e);
            if (need_mask) {
              int qi = q0 + w * 32 + m * 16 + quad * 4 + r;
              int kj = kk0 + ni * 16 + l16;
              if (kj > qi) p = 0.0f;
            }
            Ps[w][m * 16 + quad * 4 + r][ni * 16 + l16] = f2bf(p);
          }

      // ---- O += P V  (P is per-wave: no barrier, compiler waits lgkmcnt) ----
#pragma unroll
      for (int ks = 0; ks < 2; ks++) {
        s16x8 pf0 = *(const s16x8*)&Ps[w][l16][ks * 32 + quad * 8];
        s16x8 pf1 = *(const s16x8*)&Ps[w][16 + l16][ks * 32 + quad * 8];
#pragma unroll
        for (int d2 = 0; d2 < 4; d2++) {
          s16x8 vf = *(const s16x8*)&Vs[d2 * 16 + l16][ks * 32 + quad * 8];
          oacc[0][d2] = mfma16(pf0, vf, oacc[0][d2]);
          oacc[1][d2] = mfma16(pf1, vf, oacc[1][d2]);
        }
      }
    }

    // ---- epilogue for this q-tile ----
#pragma unroll
    for (int m = 0; m < 2; m++)
#pragma unroll
      for (int d2 = 0; d2 < 4; d2++)
#pragma unroll
        for (int r = 0; r < 4; r++) {
          int row = q0 + w * 32 + m * 16 + quad * 4 + r;
          int col = h * 64 + d2 * 16 + l16;
          size_t idx = (size_t)(b * SQ_ + row) * D_ + col;
          float v = oacc[m][d2][r];
          out0[idx] = v;
          atv_bf[idx] = f2bf(v);
        }
  }
}

extern "C" void kernel_launch(void* const* d_in, const int* in_sizes, int n_in,
                              void* d_out, int out_size, void* d_ws, size_t ws_size,
                              hipStream_t stream) {
  const float* q      = (const float*)d_in[0];
  const float* kv     = (const float*)d_in[1];
  const float* Wq     = (const float*)d_in[2];
  const float* Wkv    = (const float*)d_in[3];
  const float* vgamma = (const float*)d_in[4];
  const float* vbeta  = (const float*)d_in[5];
  const float* Wproj  = (const float*)d_in[6];
  float* out0 = (float*)d_out;
  float* out1 = out0 + (size_t)B_ * SQ_ * D_;

  char* p = (char*)d_ws;
  u16* q_bf  = (u16*)p; p += (size_t)B_ * SQ_ * D_ * 2;        // 8 MB
  u16* kv_bf = (u16*)p; p += (size_t)B_ * SKV_ * D_ * 2;       // 8 MB
  u16* WqT   = (u16*)p; p += (size_t)D_ * D_ * 2;              // 2 MB
  u16* WkvT  = (u16*)p; p += (size_t)2 * D_ * D_ * 2;          // 4 MB
  u16* WprT  = (u16*)p; p += (size_t)D_ * D_ * 2;              // 2 MB
  u16* qh    = (u16*)p; p += (size_t)B_ * SQ_ * D_ * 2;        // 8 MB
  u16* kvh   = (u16*)p; p += (size_t)B_ * SKV_ * 2 * D_ * 2;   // 16 MB
  u16* vt    = (u16*)p; p += (size_t)B_ * H_ * HD_ * SKV_ * 2; // 8 MB
  u16* atv   = (u16*)p; p += (size_t)B_ * SQ_ * D_ * 2;        // 8 MB

  cast_kernel<<<dim3((B_ * SQ_ * D_) / 1024), 256, 0, stream>>>(q, q_bf, B_ * SQ_ * D_);
  cast_kernel<<<dim3((B_ * SKV_ * D_) / 1024), 256, 0, stream>>>(kv, kv_bf, B_ * SKV_ * D_);
  transpose_cast<<<dim3(D_ / 32, D_ / 32), dim3(32, 8), 0, stream>>>(Wq, WqT, D_, D_);
  transpose_cast<<<dim3(2 * D_ / 32, D_ / 32), dim3(32, 8), 0, stream>>>(Wkv, WkvT, D_, 2 * D_);
  transpose_cast<<<dim3(D_ / 32, D_ / 32), dim3(32, 8), 0, stream>>>(Wproj, WprT, D_, D_);

  gemm_abt<true><<<dim3(D_ / 128, (B_ * SQ_) / 128), 256, 0, stream>>>(q_bf, WqT, qh, B_ * SQ_, D_, D_);
  gemm_abt<true><<<dim3((2 * D_) / 128, (B_ * SKV_) / 128), 256, 0, stream>>>(kv_bf, WkvT, kvh, B_ * SKV_, 2 * D_, D_);

  ln_vt_kernel<<<dim3((B_ * H_ * SKV_) / 64), 256, 0, stream>>>(kvh, vgamma, vbeta, vt);

  attn_kernel<<<dim3(8, H_, B_), 256, 0, stream>>>(qh, kvh, vt, out0, atv);

  gemm_abt<false><<<dim3(D_ / 128, (B_ * SQ_) / 128), 256, 0, stream>>>(atv, WprT, out1, B_ * SQ_, D_, D_);
}

// Round 3
// 236.502 us; speedup vs baseline: 1.8452x; 1.0800x over previous
//
#include <hip/hip_runtime.h>
#include <hip/hip_bf16.h>

#define B_ 2
#define SQ_ 2048
#define SKV_ 2048
#define D_ 1024
#define H_ 16
#define HD_ 64

typedef unsigned short u16;
typedef float f32x4 __attribute__((ext_vector_type(4)));
typedef short s16x8 __attribute__((ext_vector_type(8)));

__device__ __forceinline__ u16 f2bf(float f) {
  union { float f; unsigned u; } v; v.f = f;
  return (u16)((v.u + 0x7FFFu + ((v.u >> 16) & 1u)) >> 16);
}
__device__ __forceinline__ u16 f2bf_fast(float f) {  // round-half-up: 2 VALU ops
  union { float f; unsigned u; } v; v.f = f;
  return (u16)((v.u + 0x8000u) >> 16);
}
__device__ __forceinline__ float bf2f(u16 h) {
  union { unsigned u; float f; } v; v.u = ((unsigned)h) << 16;
  return v.f;
}
__device__ __forceinline__ f32x4 mfma16(s16x8 a, s16x8 b, f32x4 c) {
  return __builtin_amdgcn_mfma_f32_16x16x32_bf16(a, b, c, 0, 0, 0);
}

// ---------------- cast fp32 -> bf16 ----------------
__global__ __launch_bounds__(256) void cast_kernel(const float* __restrict__ in,
                                                   u16* __restrict__ out, int n) {
  int i = (blockIdx.x * 256 + threadIdx.x) * 4;
  if (i < n) {
    float4 f = *(const float4*)(in + i);
    ushort4 o;
    o.x = f2bf(f.x); o.y = f2bf(f.y); o.z = f2bf(f.z); o.w = f2bf(f.w);
    *(ushort4*)(out + i) = o;
  }
}

// ---------------- transpose + cast: in fp32 (R x C) -> out bf16 (C x R) ----------------
__global__ __launch_bounds__(256) void transpose_cast(const float* __restrict__ in,
                                                      u16* __restrict__ out, int R, int C) {
  __shared__ u16 tile[32][33];
  int c0 = blockIdx.x * 32, r0 = blockIdx.y * 32;
#pragma unroll
  for (int i = 0; i < 4; i++) {
    int r = r0 + threadIdx.y + i * 8;
    int c = c0 + threadIdx.x;
    tile[threadIdx.y + i * 8][threadIdx.x] = f2bf(in[(size_t)r * C + c]);
  }
  __syncthreads();
#pragma unroll
  for (int i = 0; i < 4; i++) {
    int rr = c0 + threadIdx.y + i * 8;  // out row = original col
    int cc = r0 + threadIdx.x;
    out[(size_t)rr * R + cc] = tile[threadIdx.x][threadIdx.y + i * 8];
  }
}

// ------- shared GEMM tile body: C(128x128) += A(128xK) * BT(128xK)^T -------
template <bool OUT_BF16>
__device__ __forceinline__ void gemm_tile_body(const u16* __restrict__ A,
                                               const u16* __restrict__ BT,
                                               void* __restrict__ Cout,
                                               int m0, int n0, int N, int K) {
  __shared__ __attribute__((aligned(16))) u16 As[128][36];
  __shared__ __attribute__((aligned(16))) u16 Bs[128][36];
  int t = threadIdx.x;
  int w = t >> 6, lane = t & 63;
  int l16 = lane & 15, quad = lane >> 4;
  int mw = (w >> 1) * 64, nw = (w & 1) * 64;
  int srow = t >> 1, scol = (t & 1) * 16;

  f32x4 acc[4][4] = {};
  uint4 ar0, ar1, br0, br1;

  const u16* ga_base = A + (size_t)(m0 + srow) * K + scol;
  const u16* gb_base = BT + (size_t)(n0 + srow) * K + scol;

  ar0 = *(const uint4*)(ga_base); ar1 = *(const uint4*)(ga_base + 8);
  br0 = *(const uint4*)(gb_base); br1 = *(const uint4*)(gb_base + 8);

  for (int kt = 0; kt < K; kt += 32) {
    __syncthreads();
    *(uint4*)&As[srow][scol] = ar0; *(uint4*)&As[srow][scol + 8] = ar1;
    *(uint4*)&Bs[srow][scol] = br0; *(uint4*)&Bs[srow][scol + 8] = br1;
    __syncthreads();
    if (kt + 32 < K) {
      ar0 = *(const uint4*)(ga_base + kt + 32); ar1 = *(const uint4*)(ga_base + kt + 40);
      br0 = *(const uint4*)(gb_base + kt + 32); br1 = *(const uint4*)(gb_base + kt + 40);
    }
    s16x8 af[4], bf[4];
#pragma unroll
    for (int i = 0; i < 4; i++) {
      af[i] = *(const s16x8*)&As[mw + i * 16 + l16][quad * 8];
      bf[i] = *(const s16x8*)&Bs[nw + i * 16 + l16][quad * 8];
    }
#pragma unroll
    for (int i = 0; i < 4; i++)
#pragma unroll
      for (int j = 0; j < 4; j++)
        acc[i][j] = mfma16(af[i], bf[j], acc[i][j]);
  }

#pragma unroll
  for (int i = 0; i < 4; i++)
#pragma unroll
    for (int j = 0; j < 4; j++) {
      int col = n0 + nw + j * 16 + l16;
#pragma unroll
      for (int r = 0; r < 4; r++) {
        int row = m0 + mw + i * 16 + quad * 4 + r;
        float v = acc[i][j][r];
        if (OUT_BF16)
          ((u16*)Cout)[(size_t)row * N + col] = f2bf(v);
        else
          ((float*)Cout)[(size_t)row * N + col] = v;
      }
    }
}

// ---- fused qh + kvh projection: 768 uniform blocks (3/CU) ----
__global__ __launch_bounds__(256) void gemm_qkv(const u16* __restrict__ q_bf,
                                                const u16* __restrict__ WqT,
                                                u16* __restrict__ qh,
                                                const u16* __restrict__ kv_bf,
                                                const u16* __restrict__ WkvT,
                                                u16* __restrict__ kvh) {
  int bx = blockIdx.x;  // 0..23 : [0,8) -> qh cols, [8,24) -> kvh cols
  if (bx < 8)
    gemm_tile_body<true>(q_bf, WqT, qh, blockIdx.y * 128, bx * 128, D_, D_);
  else
    gemm_tile_body<true>(kv_bf, WkvT, kvh, blockIdx.y * 128, (bx - 8) * 128, 2 * D_, D_);
}

// ---- proj GEMM (fp32 out) ----
__global__ __launch_bounds__(256) void gemm_proj(const u16* __restrict__ A,
                                                 const u16* __restrict__ BT,
                                                 float* __restrict__ C) {
  gemm_tile_body<false>(A, BT, C, blockIdx.y * 128, blockIdx.x * 128, D_, D_);
}

// ---------------- LayerNorm of v + transpose into vt[b,h,d,s] ----------------
__global__ __launch_bounds__(256) void ln_vt_kernel(const u16* __restrict__ kvh,  // (B*SKV) x 2048
                                                    const float* __restrict__ gamma,
                                                    const float* __restrict__ beta,
                                                    u16* __restrict__ vt) {  // (B*H*HD) x SKV
  __shared__ __attribute__((aligned(16))) u16 tile[64][72];  // [d][s]
  int bid = blockIdx.x;
  int stile = bid & 31;        // SKV/64 = 32
  int h = (bid >> 5) & 15;
  int b = bid >> 9;
  int wave = threadIdx.x >> 6, lane = threadIdx.x & 63;
  float g = gamma[lane], be = beta[lane];
#pragma unroll 4
  for (int i = 0; i < 16; i++) {
    int s = stile * 64 + wave * 16 + i;
    float x = bf2f(kvh[(size_t)(b * SKV_ + s) * 2048 + 1024 + h * 64 + lane]);
    float sum = x;
#pragma unroll
    for (int off = 32; off; off >>= 1) sum += __shfl_xor(sum, off, 64);
    float mu = sum * (1.0f / 64.0f);
    float dx = x - mu;
    float s2 = dx * dx;
#pragma unroll
    for (int off = 32; off; off >>= 1) s2 += __shfl_xor(s2, off, 64);
    float inv = rsqrtf(s2 * (1.0f / 64.0f) + 1e-5f);
    tile[lane][wave * 16 + i] = f2bf(dx * inv * g + be);
  }
  __syncthreads();
  int d = threadIdx.x >> 2, sc = (threadIdx.x & 3) * 16;
  size_t orow = ((size_t)(b * H_ + h) * 64 + d) * SKV_ + stile * 64 + sc;
  uint4 v0 = *(const uint4*)&tile[d][sc];
  uint4 v1 = *(const uint4*)&tile[d][sc + 8];
  *(uint4*)(vt + orow) = v0;
  *(uint4*)(vt + orow + 8) = v1;
}

// ---------------- attention ----------------
// 64-row Q tiles, 32 per (b,h). Block = pair (p, 31-p) -> exactly 33 kt-iters, uniform.
// Grid: x = bh (32) so bid%8 == bh%8 -> all blocks of one (b,h) share an XCD (K/V L2 reuse).
// K/V double-buffered in LDS: ONE barrier per kt. 512 blocks = 2/CU.
__global__ __launch_bounds__(256) void attn_kernel(const u16* __restrict__ qh,   // (B*SQ) x D
                                                   const u16* __restrict__ kvh,  // (B*SKV) x 2D
                                                   const u16* __restrict__ vt,   // (B*H*HD) x SKV
                                                   float* __restrict__ out0,
                                                   u16* __restrict__ atv_bf) {
  __shared__ __attribute__((aligned(16))) u16 Ks[2][64][68];   // [buf][k][d]
  __shared__ __attribute__((aligned(16))) u16 Vs[2][64][68];   // [buf][d][k]
  __shared__ __attribute__((aligned(16))) u16 Ps[4][16][68];   // per-wave P tile

  int bh = blockIdx.x;          // 0..31
  int pair = blockIdx.y;        // 0..15
  int h = bh & 15, b = bh >> 4;
  int t = threadIdx.x;
  int w = t >> 6, lane = t & 63;
  int l16 = lane & 15, quad = lane >> 4;
  int srow = t >> 2;            // 0..63 staging row
  int scol = (t & 3) * 16;      // 4 threads x 32B per 128B row

  const float C1 = -0.18033688011f;  // -0.125 * log2(e)
  const float C2 = 11.5415603272f;   // 8 * log2(e)

  for (int half = 0; half < 2; half++) {
    int qt = half ? (31 - pair) : pair;
    int q0 = qt * 64;
    int nkt = qt + 1;

    // q fragments: wave owns 16 q-rows
    s16x8 qf[2];
    {
      size_t qrow = (size_t)(b * SQ_ + q0 + w * 16 + l16);
      qf[0] = *(const s16x8*)(qh + qrow * D_ + h * 64 + quad * 8);
      qf[1] = *(const s16x8*)(qh + qrow * D_ + h * 64 + 32 + quad * 8);
    }

    f32x4 oacc[4] = {};

    const u16* gk = kvh + ((size_t)(b * SKV_) + srow) * 2048 + h * 64 + scol;
    const u16* gv = vt + ((size_t)((b * H_ + h) * 64 + srow)) * 2048 + scol;
    uint4 kr0 = *(const uint4*)gk, kr1 = *(const uint4*)(gk + 8);
    uint4 vr0 = *(const uint4*)gv, vr1 = *(const uint4*)(gv + 8);

    for (int kt = 0; kt < nkt; kt++) {
      int buf = kt & 1;
      *(uint4*)&Ks[buf][srow][scol] = kr0; *(uint4*)&Ks[buf][srow][scol + 8] = kr1;
      *(uint4*)&Vs[buf][srow][scol] = vr0; *(uint4*)&Vs[buf][srow][scol + 8] = vr1;
      __syncthreads();
      if (kt + 1 < nkt) {  // prefetch next tile into regs; lands during compute
        const u16* gk2 = gk + (size_t)(kt + 1) * 64 * 2048;
        const u16* gv2 = gv + (size_t)(kt + 1) * 64;
        kr0 = *(const uint4*)gk2; kr1 = *(const uint4*)(gk2 + 8);
        vr0 = *(const uint4*)gv2; vr1 = *(const uint4*)(gv2 + 8);
      }

      // ---- S = q k^T ----
      f32x4 sacc[4] = {};
#pragma unroll
      for (int ni = 0; ni < 4; ni++) {
        s16x8 kf0 = *(const s16x8*)&Ks[buf][ni * 16 + l16][quad * 8];
        s16x8 kf1 = *(const s16x8*)&Ks[buf][ni * 16 + l16][32 + quad * 8];
        sacc[ni] = mfma16(qf[0], kf0, sacc[ni]);
        sacc[ni] = mfma16(qf[1], kf1, sacc[ni]);
      }

      // ---- P = sigmoid(S/8 - 8) * causal ----
      int kk0 = kt * 64;
      bool need_mask = (kt == nkt - 1);  // only the diagonal tile masks
#pragma unroll
      for (int ni = 0; ni < 4; ni++)
#pragma unroll
        for (int r = 0; r < 4; r++) {
          float s = sacc[ni][r];
          float e = __builtin_amdgcn_exp2f(s * C1 + C2);  // e^{-(s/8-8)} base-2 form
          float p = __builtin_amdgcn_rcpf(1.0f + e);
          if (need_mask) {
            int qi = q0 + w * 16 + quad * 4 + r;
            int kj = kk0 + ni * 16 + l16;
            if (kj > qi) p = 0.0f;
          }
          Ps[w][quad * 4 + r][ni * 16 + l16] = f2bf_fast(p);
        }

      // ---- O += P V (per-wave P: no barrier, lgkmcnt ordering suffices) ----
#pragma unroll
      for (int ks = 0; ks < 2; ks++) {
        s16x8 pf = *(const s16x8*)&Ps[w][l16][ks * 32 + quad * 8];
#pragma unroll
        for (int d2 = 0; d2 < 4; d2++) {
          s16x8 vf = *(const s16x8*)&Vs[buf][d2 * 16 + l16][ks * 32 + quad * 8];
          oacc[d2] = mfma16(pf, vf, oacc[d2]);
        }
      }
    }

    // ---- epilogue ----
#pragma unroll
    for (int d2 = 0; d2 < 4; d2++)
#pragma unroll
      for (int r = 0; r < 4; r++) {
        int row = q0 + w * 16 + quad * 4 + r;
        int col = h * 64 + d2 * 16 + l16;
        size_t idx = (size_t)(b * SQ_ + row) * D_ + col;
        float v = oacc[d2][r];
        out0[idx] = v;
        atv_bf[idx] = f2bf(v);
      }
    __syncthreads();  // protect LDS buffers before next half reuses them
  }
}

extern "C" void kernel_launch(void* const* d_in, const int* in_sizes, int n_in,
                              void* d_out, int out_size, void* d_ws, size_t ws_size,
                              hipStream_t stream) {
  const float* q      = (const float*)d_in[0];
  const float* kv     = (const float*)d_in[1];
  const float* Wq     = (const float*)d_in[2];
  const float* Wkv    = (const float*)d_in[3];
  const float* vgamma = (const float*)d_in[4];
  const float* vbeta  = (const float*)d_in[5];
  const float* Wproj  = (const float*)d_in[6];
  float* out0 = (float*)d_out;
  float* out1 = out0 + (size_t)B_ * SQ_ * D_;

  char* p = (char*)d_ws;
  u16* q_bf  = (u16*)p; p += (size_t)B_ * SQ_ * D_ * 2;        // 8 MB
  u16* kv_bf = (u16*)p; p += (size_t)B_ * SKV_ * D_ * 2;       // 8 MB
  u16* WqT   = (u16*)p; p += (size_t)D_ * D_ * 2;              // 2 MB
  u16* WkvT  = (u16*)p; p += (size_t)2 * D_ * D_ * 2;          // 4 MB
  u16* WprT  = (u16*)p; p += (size_t)D_ * D_ * 2;              // 2 MB
  u16* qh    = (u16*)p; p += (size_t)B_ * SQ_ * D_ * 2;        // 8 MB
  u16* kvh   = (u16*)p; p += (size_t)B_ * SKV_ * 2 * D_ * 2;   // 16 MB
  u16* vt    = (u16*)p; p += (size_t)B_ * H_ * HD_ * SKV_ * 2; // 8 MB
  u16* atv   = (u16*)p; p += (size_t)B_ * SQ_ * D_ * 2;        // 8 MB

  cast_kernel<<<dim3((B_ * SQ_ * D_) / 1024), 256, 0, stream>>>(q, q_bf, B_ * SQ_ * D_);
  cast_kernel<<<dim3((B_ * SKV_ * D_) / 1024), 256, 0, stream>>>(kv, kv_bf, B_ * SKV_ * D_);
  transpose_cast<<<dim3(D_ / 32, D_ / 32), dim3(32, 8), 0, stream>>>(Wq, WqT, D_, D_);
  transpose_cast<<<dim3(2 * D_ / 32, D_ / 32), dim3(32, 8), 0, stream>>>(Wkv, WkvT, D_, 2 * D_);
  transpose_cast<<<dim3(D_ / 32, D_ / 32), dim3(32, 8), 0, stream>>>(Wproj, WprT, D_, D_);

  gemm_qkv<<<dim3(24, 32), 256, 0, stream>>>(q_bf, WqT, qh, kv_bf, WkvT, kvh);

  ln_vt_kernel<<<dim3((B_ * H_ * SKV_) / 64), 256, 0, stream>>>(kvh, vgamma, vbeta, vt);

  attn_kernel<<<dim3(32, 16), 256, 0, stream>>>(qh, kvh, vt, out0, atv);

  gemm_proj<<<dim3(8, 32), 256, 0, stream>>>(atv, WprT, out1);
}

// Round 5
// 216.521 us; speedup vs baseline: 2.0155x; 1.0923x over previous
//
#include <hip/hip_runtime.h>
#include <hip/hip_bf16.h>

#define B_ 2
#define SQ_ 2048
#define SKV_ 2048
#define D_ 1024
#define H_ 16
#define HD_ 64

typedef unsigned short u16;
typedef float f32x4 __attribute__((ext_vector_type(4)));
typedef float f32x16 __attribute__((ext_vector_type(16)));
typedef short s16x8 __attribute__((ext_vector_type(8)));

__device__ __forceinline__ u16 f2bf(float f) {
  union { float f; unsigned u; } v; v.f = f;
  return (u16)((v.u + 0x7FFFu + ((v.u >> 16) & 1u)) >> 16);
}
__device__ __forceinline__ u16 f2bf_fast(float f) {
  union { float f; unsigned u; } v; v.f = f;
  return (u16)((v.u + 0x8000u) >> 16);
}
__device__ __forceinline__ float bf2f(u16 h) {
  union { unsigned u; float f; } v; v.u = ((unsigned)h) << 16;
  return v.f;
}
__device__ __forceinline__ f32x4 mfma16(s16x8 a, s16x8 b, f32x4 c) {
  return __builtin_amdgcn_mfma_f32_16x16x32_bf16(a, b, c, 0, 0, 0);
}
__device__ __forceinline__ f32x16 mfma32(s16x8 a, s16x8 b, f32x16 c) {
  return __builtin_amdgcn_mfma_f32_32x32x16_bf16(a, b, c, 0, 0, 0);
}
// async 16B/lane global -> LDS (dest = wave-uniform base + lane*16)
__device__ __forceinline__ void async16(const u16* g, u16* l) {
  __builtin_amdgcn_global_load_lds(
      (const __attribute__((address_space(1))) unsigned int*)g,
      (__attribute__((address_space(3))) unsigned int*)l, 16, 0, 0);
}

// ---------------- fused prep: cast q, cast kv, transpose 3 weights ----------------
__device__ __forceinline__ void tr_tile(const float* __restrict__ in, u16* __restrict__ out,
                                        int R, int C, int cx, int ry, int t) {
  __shared__ u16 tile[32][33];
  int tx = t & 31, ty = t >> 5;
  int c0 = cx * 32, r0 = ry * 32;
#pragma unroll
  for (int i = 0; i < 4; i++)
    tile[ty + i * 8][tx] = f2bf(in[(size_t)(r0 + ty + i * 8) * C + c0 + tx]);
  __syncthreads();
#pragma unroll
  for (int i = 0; i < 4; i++)
    out[(size_t)(c0 + ty + i * 8) * R + r0 + tx] = tile[tx][ty + i * 8];
}

__device__ __forceinline__ void cast4(const float* __restrict__ in, u16* __restrict__ out,
                                      int i) {
  float4 f = *(const float4*)(in + i);
  ushort4 o;
  o.x = f2bf(f.x); o.y = f2bf(f.y); o.z = f2bf(f.z); o.w = f2bf(f.w);
  *(ushort4*)(out + i) = o;
}

// grid ranges (256 thr, 1024 elems/block for casts):
//   [0,4096)      q cast      (4096*1024 = 4.19M = B*SQ*D)
//   [4096,8192)   kv cast
//   [8192,9216)   Wq  transpose (32x32 tiles: 32*32=1024 blocks)
//   [9216,11264)  Wkv transpose (64 col-tiles x 32 row-tiles = 2048)
//   [11264,12288) Wproj transpose
__global__ __launch_bounds__(256) void prep_kernel(
    const float* __restrict__ q, u16* __restrict__ q_bf,
    const float* __restrict__ kv, u16* __restrict__ kv_bf,
    const float* __restrict__ Wq, u16* __restrict__ WqT,
    const float* __restrict__ Wkv, u16* __restrict__ WkvT,
    const float* __restrict__ Wproj, u16* __restrict__ WprT) {
  int bid = blockIdx.x, t = threadIdx.x;
  if (bid < 4096) {
    cast4(q, q_bf, bid * 1024 + t * 4);
  } else if (bid < 8192) {
    cast4(kv, kv_bf, (bid - 4096) * 1024 + t * 4);
  } else if (bid < 9216) {
    int b2 = bid - 8192;
    tr_tile(Wq, WqT, 1024, 1024, b2 & 31, b2 >> 5, t);
  } else if (bid < 11264) {
    int b2 = bid - 9216;
    tr_tile(Wkv, WkvT, 1024, 2048, b2 & 63, b2 >> 6, t);
  } else {
    int b2 = bid - 11264;
    tr_tile(Wproj, WprT, 1024, 1024, b2 & 31, b2 >> 5, t);
  }
}

// ------- m97-style GEMM body: C(BMxBN) = A(BM x K) * BT(BN x K)^T -------
template <int BM, int BN, bool OUT_BF16>
__device__ __forceinline__ void gemm_body(const u16* __restrict__ A,
                                          const u16* __restrict__ BT,
                                          void* __restrict__ Cout,
                                          int m0, int n0, int N, int K) {
  __shared__ __attribute__((aligned(16))) u16 As[BM][32];
  __shared__ __attribute__((aligned(16))) u16 Bs[BN][32];
  constexpr int AM = BM / 32, AN = BN / 32;  // frags per wave (2x2 wave grid)
  int t = threadIdx.x, w = t >> 6, lane = t & 63;
  int l16 = lane & 15, quad = lane >> 4;
  int mw = (w >> 1) * (BM / 2), nw = (w & 1) * (BN / 2);
  int grow = w * 16 + (lane >> 2);   // staging row within 64-row slab
  int gcol = (lane & 3) * 8;         // staging col (elements)

  f32x4 acc[AM][AN] = {};

  for (int kt = 0; kt < K; kt += 32) {
    __syncthreads();  // all waves done reading previous slab
#pragma unroll
    for (int j = 0; j < BM / 64; j++)
      async16(A + (size_t)(m0 + j * 64 + grow) * K + kt + gcol, &As[j * 64 + w * 16][0]);
#pragma unroll
    for (int j = 0; j < BN / 64; j++)
      async16(BT + (size_t)(n0 + j * 64 + grow) * K + kt + gcol, &Bs[j * 64 + w * 16][0]);
    __syncthreads();  // drains vmcnt -> LDS visible
    s16x8 af[AM], bf[AN];
#pragma unroll
    for (int i = 0; i < AM; i++) af[i] = *(const s16x8*)&As[mw + i * 16 + l16][quad * 8];
#pragma unroll
    for (int j = 0; j < AN; j++) bf[j] = *(const s16x8*)&Bs[nw + j * 16 + l16][quad * 8];
#pragma unroll
    for (int i = 0; i < AM; i++)
#pragma unroll
      for (int j = 0; j < AN; j++)
        acc[i][j] = mfma16(af[i], bf[j], acc[i][j]);
  }

#pragma unroll
  for (int i = 0; i < AM; i++)
#pragma unroll
    for (int j = 0; j < AN; j++) {
      int col = n0 + nw + j * 16 + l16;
#pragma unroll
      for (int r = 0; r < 4; r++) {
        int row = m0 + mw + i * 16 + quad * 4 + r;
        float v = acc[i][j][r];
        if (OUT_BF16)
          ((u16*)Cout)[(size_t)row * N + col] = f2bf(v);
        else
          ((float*)Cout)[(size_t)row * N + col] = v;
      }
    }
}

__global__ __launch_bounds__(256, 3) void gemm_qkv(const u16* __restrict__ q_bf,
                                                   const u16* __restrict__ WqT,
                                                   u16* __restrict__ qh,
                                                   const u16* __restrict__ kv_bf,
                                                   const u16* __restrict__ WkvT,
                                                   u16* __restrict__ kvh) {
  int bx = blockIdx.x;
  if (bx < 8)
    gemm_body<128, 128, true>(q_bf, WqT, qh, blockIdx.y * 128, bx * 128, D_, D_);
  else
    gemm_body<128, 128, true>(kv_bf, WkvT, kvh, blockIdx.y * 128, (bx - 8) * 128, 2 * D_, D_);
}

__global__ __launch_bounds__(256, 3) void gemm_proj(const u16* __restrict__ A,
                                                    const u16* __restrict__ BT,
                                                    float* __restrict__ C) {
  gemm_body<64, 128, false>(A, BT, C, blockIdx.y * 64, blockIdx.x * 128, D_, D_);
}

// ---------------- LayerNorm of v + transpose into vt[b,h,d,s] ----------------
__global__ __launch_bounds__(256) void ln_vt_kernel(const u16* __restrict__ kvh,
                                                    const float* __restrict__ gamma,
                                                    const float* __restrict__ beta,
                                                    u16* __restrict__ vt) {
  __shared__ __attribute__((aligned(16))) u16 tile[64][72];  // [d][s]
  int bid = blockIdx.x;
  int stile = bid & 31;
  int h = (bid >> 5) & 15;
  int b = bid >> 9;
  int wave = threadIdx.x >> 6, lane = threadIdx.x & 63;
  float g = gamma[lane], be = beta[lane];
#pragma unroll 4
  for (int i = 0; i < 16; i++) {
    int s = stile * 64 + wave * 16 + i;
    float x = bf2f(kvh[(size_t)(b * SKV_ + s) * 2048 + 1024 + h * 64 + lane]);
    float sum = x;
#pragma unroll
    for (int off = 32; off; off >>= 1) sum += __shfl_xor(sum, off, 64);
    float mu = sum * (1.0f / 64.0f);
    float dx = x - mu;
    float s2 = dx * dx;
#pragma unroll
    for (int off = 32; off; off >>= 1) s2 += __shfl_xor(s2, off, 64);
    float inv = rsqrtf(s2 * (1.0f / 64.0f) + 1e-5f);
    tile[lane][wave * 16 + i] = f2bf(dx * inv * g + be);
  }
  __syncthreads();
  int d = threadIdx.x >> 2, sc = (threadIdx.x & 3) * 16;
  size_t orow = ((size_t)(b * H_ + h) * 64 + d) * SKV_ + stile * 64 + sc;
  uint4 v0 = *(const uint4*)&tile[d][sc];
  uint4 v1 = *(const uint4*)&tile[d][sc + 8];
  *(uint4*)(vt + orow) = v0;
  *(uint4*)(vt + orow + 8) = v1;
}

// ---------------- attention: 32x32 MFMA, S^T trick ----------------
// Block: q-tile 128 (4 waves x q32 strip), kv tiles of 64, LDS double-buffered.
// Pair (p, 15-p) -> every block exactly 34 kv-iters. Grid (32 bh, 8 pairs) = 256 blocks.
// S^T = mfma(A=K, B=Q): C-layout row=k gives 4 consecutive k per reg-group ->
// P packs as ds_write_b64 into Ps[q][k], which is exactly PV's A-operand layout.
__global__ __launch_bounds__(256, 1) void attn_kernel(const u16* __restrict__ qh,
                                                      const u16* __restrict__ kvh,
                                                      const u16* __restrict__ vt,
                                                      float* __restrict__ out0,
                                                      u16* __restrict__ atv_bf) {
  // strides: 72 elems = 144 B = 36 banks === 4 (mod 32) -> conflict-free column b128 reads
  __shared__ __attribute__((aligned(16))) u16 Ks[2][64][72];  // [buf][kv][d]
  __shared__ __attribute__((aligned(16))) u16 Vs[2][64][72];  // [buf][d][kv]
  __shared__ __attribute__((aligned(16))) u16 Ps[4][32][72];  // [wave][q][k]

  int bh = blockIdx.x;
  int pair = blockIdx.y;  // 0..7
  int h = bh & 15, b = bh >> 4;
  int t = threadIdx.x;
  int w = t >> 6, lane = t & 63;
  int l31 = lane & 31, hi = lane >> 5;
  int srow = t >> 2;            // staging row 0..63
  int scol = (t & 3) * 16;      // staging col (elements), +0/+8 chunks

  const float C1 = -0.18033688011f;  // -0.125 * log2(e)
  const float C2 = 11.5415603272f;   // 8 * log2(e)

  const u16* gkb = kvh + ((size_t)(b * SKV_) + srow) * 2048 + h * 64 + scol;
  const u16* gvb = vt + ((size_t)((b * H_ + h) * 64 + srow)) * 2048 + scol;

  for (int half = 0; half < 2; half++) {
    int qt = half ? (15 - pair) : pair;
    int q0 = qt * 128;
    int nkv = 2 * qt + 2;

    // Q fragments (B-operand): lane: q = q0+w*32+l31, d = c*16 + hi*8 + j
    s16x8 qf[4];
    {
      const u16* qp = qh + (size_t)(b * SQ_ + q0 + w * 32 + l31) * D_ + h * 64 + hi * 8;
#pragma unroll
      for (int c = 0; c < 4; c++) qf[c] = *(const s16x8*)(qp + c * 16);
    }

    f32x16 oacc[2] = {};

    uint4 kr0 = *(const uint4*)gkb, kr1 = *(const uint4*)(gkb + 8);
    uint4 vr0 = *(const uint4*)gvb, vr1 = *(const uint4*)(gvb + 8);

    for (int kt = 0; kt < nkv; kt++) {
      int buf = kt & 1;
      *(uint4*)&Ks[buf][srow][scol] = kr0; *(uint4*)&Ks[buf][srow][scol + 8] = kr1;
      *(uint4*)&Vs[buf][srow][scol] = vr0; *(uint4*)&Vs[buf][srow][scol + 8] = vr1;
      __syncthreads();
      if (kt + 1 < nkv) {
        const u16* gk2 = gkb + (size_t)(kt + 1) * 64 * 2048;
        const u16* gv2 = gvb + (size_t)(kt + 1) * 64;
        kr0 = *(const uint4*)gk2; kr1 = *(const uint4*)(gk2 + 8);
        vr0 = *(const uint4*)gv2; vr1 = *(const uint4*)(gv2 + 8);
      }

      int kk0 = kt * 64;
      bool need_mask = (kt >= 2 * qt);
      int qi = q0 + w * 32 + l31;

      // ---- S^T (k64 x q32): 2 k-tiles x 4 d-chunks ----
#pragma unroll
      for (int ktile = 0; ktile < 2; ktile++) {
        f32x16 st = {};
#pragma unroll
        for (int c = 0; c < 4; c++) {
          s16x8 kf = *(const s16x8*)&Ks[buf][ktile * 32 + l31][c * 16 + hi * 8];
          st = mfma32(kf, qf[c], st);
        }
        // sigmoid + mask + pack 4 consecutive k -> ds_write_b64 into Ps[q][k]
#pragma unroll
        for (int g = 0; g < 4; g++) {
          unsigned lo, hi2;
          u16 pk[4];
#pragma unroll
          for (int i = 0; i < 4; i++) {
            float s = st[4 * g + i];
            float e = __builtin_amdgcn_exp2f(s * C1 + C2);
            float p = __builtin_amdgcn_rcpf(1.0f + e);
            if (need_mask) {
              int kj = kk0 + ktile * 32 + 8 * g + 4 * hi + i;
              if (kj > qi) p = 0.0f;
            }
            pk[i] = f2bf_fast(p);
          }
          lo = (unsigned)pk[0] | ((unsigned)pk[1] << 16);
          hi2 = (unsigned)pk[2] | ((unsigned)pk[3] << 16);
          uint2 pv; pv.x = lo; pv.y = hi2;
          *(uint2*)&Ps[w][l31][ktile * 32 + 8 * g + 4 * hi] = pv;
        }
      }

      // ---- O += P V : A = Ps[q][k] (per-wave, lgkmcnt-ordered), B = Vs[d][k] ----
      s16x8 pa[4];
#pragma unroll
      for (int kc = 0; kc < 4; kc++)
        pa[kc] = *(const s16x8*)&Ps[w][l31][kc * 16 + hi * 8];
#pragma unroll
      for (int dt = 0; dt < 2; dt++)
#pragma unroll
        for (int kc = 0; kc < 4; kc++) {
          s16x8 vf = *(const s16x8*)&Vs[buf][dt * 32 + l31][kc * 16 + hi * 8];
          oacc[dt] = mfma32(pa[kc], vf, oacc[dt]);
        }
    }

    // ---- epilogue: O C/D layout col=d, row=(reg&3)+8*(reg>>2)+4*hi ----
#pragma unroll
    for (int dt = 0; dt < 2; dt++)
#pragma unroll
      for (int reg = 0; reg < 16; reg++) {
        int ql = (reg & 3) + 8 * (reg >> 2) + 4 * hi;
        int row = q0 + w * 32 + ql;
        int col = h * 64 + dt * 32 + l31;
        size_t idx = (size_t)(b * SQ_ + row) * D_ + col;
        float v = oacc[dt][reg];
        out0[idx] = v;
        atv_bf[idx] = f2bf(v);
      }
    __syncthreads();  // LDS buffers free before next half
  }
}

extern "C" void kernel_launch(void* const* d_in, const int* in_sizes, int n_in,
                              void* d_out, int out_size, void* d_ws, size_t ws_size,
                              hipStream_t stream) {
  const float* q      = (const float*)d_in[0];
  const float* kv     = (const float*)d_in[1];
  const float* Wq     = (const float*)d_in[2];
  const float* Wkv    = (const float*)d_in[3];
  const float* vgamma = (const float*)d_in[4];
  const float* vbeta  = (const float*)d_in[5];
  const float* Wproj  = (const float*)d_in[6];
  float* out0 = (float*)d_out;
  float* out1 = out0 + (size_t)B_ * SQ_ * D_;

  char* p = (char*)d_ws;
  u16* q_bf  = (u16*)p; p += (size_t)B_ * SQ_ * D_ * 2;
  u16* kv_bf = (u16*)p; p += (size_t)B_ * SKV_ * D_ * 2;
  u16* WqT   = (u16*)p; p += (size_t)D_ * D_ * 2;
  u16* WkvT  = (u16*)p; p += (size_t)2 * D_ * D_ * 2;
  u16* WprT  = (u16*)p; p += (size_t)D_ * D_ * 2;
  u16* qh    = (u16*)p; p += (size_t)B_ * SQ_ * D_ * 2;
  u16* kvh   = (u16*)p; p += (size_t)B_ * SKV_ * 2 * D_ * 2;
  u16* vt    = (u16*)p; p += (size_t)B_ * H_ * HD_ * SKV_ * 2;
  u16* atv   = (u16*)p; p += (size_t)B_ * SQ_ * D_ * 2;

  prep_kernel<<<dim3(12288), 256, 0, stream>>>(q, q_bf, kv, kv_bf, Wq, WqT, Wkv, WkvT, Wproj, WprT);

  gemm_qkv<<<dim3(24, 32), 256, 0, stream>>>(q_bf, WqT, qh, kv_bf, WkvT, kvh);

  ln_vt_kernel<<<dim3((B_ * H_ * SKV_) / 64), 256, 0, stream>>>(kvh, vgamma, vbeta, vt);

  attn_kernel<<<dim3(32, 8), 256, 0, stream>>>(qh, kvh, vt, out0, atv);

  gemm_proj<<<dim3(8, 64), 256, 0, stream>>>(atv, WprT, out1);
}

// Round 6
// 204.482 us; speedup vs baseline: 2.1342x; 1.0589x over previous
//
#include <hip/hip_runtime.h>
#include <hip/hip_bf16.h>

#define B_ 2
#define SQ_ 2048
#define SKV_ 2048
#define D_ 1024
#define H_ 16
#define HD_ 64

typedef unsigned short u16;
typedef float f32x4 __attribute__((ext_vector_type(4)));
typedef float f32x16 __attribute__((ext_vector_type(16)));
typedef short s16x8 __attribute__((ext_vector_type(8)));

__device__ __forceinline__ u16 f2bf(float f) {
  union { float f; unsigned u; } v; v.f = f;
  return (u16)((v.u + 0x7FFFu + ((v.u >> 16) & 1u)) >> 16);
}
__device__ __forceinline__ u16 f2bf_fast(float f) {
  union { float f; unsigned u; } v; v.f = f;
  return (u16)((v.u + 0x8000u) >> 16);
}
__device__ __forceinline__ float bf2f(u16 h) {
  union { unsigned u; float f; } v; v.u = ((unsigned)h) << 16;
  return v.f;
}
__device__ __forceinline__ f32x4 mfma16(s16x8 a, s16x8 b, f32x4 c) {
  return __builtin_amdgcn_mfma_f32_16x16x32_bf16(a, b, c, 0, 0, 0);
}
__device__ __forceinline__ f32x16 mfma32(s16x8 a, s16x8 b, f32x16 c) {
  return __builtin_amdgcn_mfma_f32_32x32x16_bf16(a, b, c, 0, 0, 0);
}
// async 16B/lane global -> LDS (dest = wave-uniform base + lane*16)
__device__ __forceinline__ void async16(const u16* g, u16* l) {
  __builtin_amdgcn_global_load_lds(
      (const __attribute__((address_space(1))) unsigned int*)g,
      (__attribute__((address_space(3))) unsigned int*)l, 16, 0, 0);
}

// ---------------- fused prep: cast q, cast kv, transpose 3 weights ----------------
__device__ __forceinline__ void tr_tile(const float* __restrict__ in, u16* __restrict__ out,
                                        int R, int C, int cx, int ry, int t) {
  __shared__ u16 tile[32][33];
  int tx = t & 31, ty = t >> 5;
  int c0 = cx * 32, r0 = ry * 32;
#pragma unroll
  for (int i = 0; i < 4; i++)
    tile[ty + i * 8][tx] = f2bf(in[(size_t)(r0 + ty + i * 8) * C + c0 + tx]);
  __syncthreads();
#pragma unroll
  for (int i = 0; i < 4; i++)
    out[(size_t)(c0 + ty + i * 8) * R + r0 + tx] = tile[tx][ty + i * 8];
}

__device__ __forceinline__ void cast4(const float* __restrict__ in, u16* __restrict__ out,
                                      int i) {
  float4 f = *(const float4*)(in + i);
  ushort4 o;
  o.x = f2bf(f.x); o.y = f2bf(f.y); o.z = f2bf(f.z); o.w = f2bf(f.w);
  *(ushort4*)(out + i) = o;
}

__global__ __launch_bounds__(256) void prep_kernel(
    const float* __restrict__ q, u16* __restrict__ q_bf,
    const float* __restrict__ kv, u16* __restrict__ kv_bf,
    const float* __restrict__ Wq, u16* __restrict__ WqT,
    const float* __restrict__ Wkv, u16* __restrict__ WkvT,
    const float* __restrict__ Wproj, u16* __restrict__ WprT) {
  int bid = blockIdx.x, t = threadIdx.x;
  if (bid < 4096) {
    cast4(q, q_bf, bid * 1024 + t * 4);
  } else if (bid < 8192) {
    cast4(kv, kv_bf, (bid - 4096) * 1024 + t * 4);
  } else if (bid < 9216) {
    int b2 = bid - 8192;
    tr_tile(Wq, WqT, 1024, 1024, b2 & 31, b2 >> 5, t);
  } else if (bid < 11264) {
    int b2 = bid - 9216;
    tr_tile(Wkv, WkvT, 1024, 2048, b2 & 63, b2 >> 6, t);
  } else {
    int b2 = bid - 11264;
    tr_tile(Wproj, WprT, 1024, 1024, b2 & 31, b2 >> 5, t);
  }
}

// ------- m97-style GEMM body: C(BMxBN) = A(BM x K) * BT(BN x K)^T -------
template <int BM, int BN, bool OUT_BF16>
__device__ __forceinline__ void gemm_body(const u16* __restrict__ A,
                                          const u16* __restrict__ BT,
                                          void* __restrict__ Cout,
                                          int m0, int n0, int N, int K) {
  __shared__ __attribute__((aligned(16))) u16 As[BM][32];
  __shared__ __attribute__((aligned(16))) u16 Bs[BN][32];
  constexpr int AM = BM / 32, AN = BN / 32;
  int t = threadIdx.x, w = t >> 6, lane = t & 63;
  int l16 = lane & 15, quad = lane >> 4;
  int mw = (w >> 1) * (BM / 2), nw = (w & 1) * (BN / 2);
  int grow = w * 16 + (lane >> 2);
  int gcol = (lane & 3) * 8;

  f32x4 acc[AM][AN] = {};

  for (int kt = 0; kt < K; kt += 32) {
    __syncthreads();
#pragma unroll
    for (int j = 0; j < BM / 64; j++)
      async16(A + (size_t)(m0 + j * 64 + grow) * K + kt + gcol, &As[j * 64 + w * 16][0]);
#pragma unroll
    for (int j = 0; j < BN / 64; j++)
      async16(BT + (size_t)(n0 + j * 64 + grow) * K + kt + gcol, &Bs[j * 64 + w * 16][0]);
    __syncthreads();
    s16x8 af[AM], bf[AN];
#pragma unroll
    for (int i = 0; i < AM; i++) af[i] = *(const s16x8*)&As[mw + i * 16 + l16][quad * 8];
#pragma unroll
    for (int j = 0; j < AN; j++) bf[j] = *(const s16x8*)&Bs[nw + j * 16 + l16][quad * 8];
#pragma unroll
    for (int i = 0; i < AM; i++)
#pragma unroll
      for (int j = 0; j < AN; j++)
        acc[i][j] = mfma16(af[i], bf[j], acc[i][j]);
  }

#pragma unroll
  for (int i = 0; i < AM; i++)
#pragma unroll
    for (int j = 0; j < AN; j++) {
      int col = n0 + nw + j * 16 + l16;
#pragma unroll
      for (int r = 0; r < 4; r++) {
        int row = m0 + mw + i * 16 + quad * 4 + r;
        float v = acc[i][j][r];
        if (OUT_BF16)
          ((u16*)Cout)[(size_t)row * N + col] = f2bf(v);
        else
          ((float*)Cout)[(size_t)row * N + col] = v;
      }
    }
}

__global__ __launch_bounds__(256, 3) void gemm_qkv(const u16* __restrict__ q_bf,
                                                   const u16* __restrict__ WqT,
                                                   u16* __restrict__ qh,
                                                   const u16* __restrict__ kv_bf,
                                                   const u16* __restrict__ WkvT,
                                                   u16* __restrict__ kvh) {
  int bx = blockIdx.x;
  if (bx < 8)
    gemm_body<128, 128, true>(q_bf, WqT, qh, blockIdx.y * 128, bx * 128, D_, D_);
  else
    gemm_body<128, 128, true>(kv_bf, WkvT, kvh, blockIdx.y * 128, (bx - 8) * 128, 2 * D_, D_);
}

__global__ __launch_bounds__(256, 3) void gemm_proj(const u16* __restrict__ A,
                                                    const u16* __restrict__ BT,
                                                    float* __restrict__ C) {
  gemm_body<64, 128, false>(A, BT, C, blockIdx.y * 64, blockIdx.x * 128, D_, D_);
}

// ---------------- LayerNorm of v + transpose into vt[b,h,d,s] ----------------
__global__ __launch_bounds__(256) void ln_vt_kernel(const u16* __restrict__ kvh,
                                                    const float* __restrict__ gamma,
                                                    const float* __restrict__ beta,
                                                    u16* __restrict__ vt) {
  __shared__ __attribute__((aligned(16))) u16 tile[64][72];  // [d][s]
  int bid = blockIdx.x;
  int stile = bid & 31;
  int h = (bid >> 5) & 15;
  int b = bid >> 9;
  int wave = threadIdx.x >> 6, lane = threadIdx.x & 63;
  float g = gamma[lane], be = beta[lane];
#pragma unroll 4
  for (int i = 0; i < 16; i++) {
    int s = stile * 64 + wave * 16 + i;
    float x = bf2f(kvh[(size_t)(b * SKV_ + s) * 2048 + 1024 + h * 64 + lane]);
    float sum = x;
#pragma unroll
    for (int off = 32; off; off >>= 1) sum += __shfl_xor(sum, off, 64);
    float mu = sum * (1.0f / 64.0f);
    float dx = x - mu;
    float s2 = dx * dx;
#pragma unroll
    for (int off = 32; off; off >>= 1) s2 += __shfl_xor(s2, off, 64);
    float inv = rsqrtf(s2 * (1.0f / 64.0f) + 1e-5f);
    tile[lane][wave * 16 + i] = f2bf(dx * inv * g + be);
  }
  __syncthreads();
  int d = threadIdx.x >> 2, sc = (threadIdx.x & 3) * 16;
  size_t orow = ((size_t)(b * H_ + h) * 64 + d) * SKV_ + stile * 64 + sc;
  uint4 v0 = *(const uint4*)&tile[d][sc];
  uint4 v1 = *(const uint4*)&tile[d][sc + 8];
  *(uint4*)(vt + orow) = v0;
  *(uint4*)(vt + orow + 8) = v1;
}

// ---------------- attention: q64 tiles, 512 blocks (2/CU), wave = (q-strip, k-half) ----------
// Pair (p, 31-p): every block exactly 33 kv64 iterations, uniform. Grid (32 bh, 16 pairs).
// Wave w: qs = w&1 (q32 strip), kh = w>>1 (k32 half). Each wave: S^T(k32 x q32) via
// mfma32(A=K,B=Q) -> sigmoid -> b64-pack into Ps[q][k] (PV A-operand layout) ->
// partial O over its k-half. Epilogue reduces the two k-halves through LDS scratch.
// LDS strides 68/36/66: measured conflict-free family (stride = 2 mod 32 banks).
__global__ __launch_bounds__(256, 2) void attn_kernel(const u16* __restrict__ qh,
                                                      const u16* __restrict__ kvh,
                                                      const u16* __restrict__ vt,
                                                      float* __restrict__ out0,
                                                      u16* __restrict__ atv_bf) {
  __shared__ __attribute__((aligned(16))) u16 Ks[2][64][68];  // [buf][kv][d] 17408 B
  __shared__ __attribute__((aligned(16))) u16 Vs[2][64][68];  // [buf][d][kv] 17408 B
  __shared__ __attribute__((aligned(16))) u16 Ps[4][32][36];  // [wave][q][k32] 9216 B

  int bh = blockIdx.x;          // 0..31
  int pair = blockIdx.y;        // 0..15
  int h = bh & 15, b = bh >> 4;
  int t = threadIdx.x;
  int w = t >> 6, lane = t & 63;
  int l31 = lane & 31, hi = lane >> 5;
  int qs = w & 1, kh = w >> 1;
  int srow = t >> 2;            // staging row 0..63
  int scol = (t & 3) * 16;      // staging col (elements)

  const float C1 = -0.18033688011f;  // -0.125 * log2(e)
  const float C2 = 11.5415603272f;   // 8 * log2(e)

  const u16* gkb = kvh + ((size_t)(b * SKV_) + srow) * 2048 + h * 64 + scol;
  const u16* gvb = vt + ((size_t)((b * H_ + h) * 64 + srow)) * 2048 + scol;
  float* Osc = (float*)&Ks[0][0][0];  // epilogue scratch alias: 2*32*66*4 = 16896 <= 17408

  for (int half = 0; half < 2; half++) {
    int qt = half ? (31 - pair) : pair;
    int q0 = qt * 64;
    int nkv = qt + 1;

    // Q fragments (B-operand): lane q = q0 + qs*32 + l31, k_dim d = c*16 + hi*8 + j
    s16x8 qf[4];
    {
      const u16* qp = qh + (size_t)(b * SQ_ + q0 + qs * 32 + l31) * D_ + h * 64 + hi * 8;
#pragma unroll
      for (int c = 0; c < 4; c++) qf[c] = *(const s16x8*)(qp + c * 16);
    }

    f32x16 oacc[2] = {};  // partial O (this wave's k-half): [dt] 32q x 32d

    uint4 kr0 = *(const uint4*)gkb, kr1 = *(const uint4*)(gkb + 8);
    uint4 vr0 = *(const uint4*)gvb, vr1 = *(const uint4*)(gvb + 8);

    for (int kt = 0; kt < nkv; kt++) {
      int buf = kt & 1;
      *(uint4*)&Ks[buf][srow][scol] = kr0; *(uint4*)&Ks[buf][srow][scol + 8] = kr1;
      *(uint4*)&Vs[buf][srow][scol] = vr0; *(uint4*)&Vs[buf][srow][scol + 8] = vr1;
      __syncthreads();  // also separates kt-2 reads from this kt's writes (dbuf)
      if (kt + 1 < nkv) {
        const u16* gk2 = gkb + (size_t)(kt + 1) * 64 * 2048;
        const u16* gv2 = gvb + (size_t)(kt + 1) * 64;
        kr0 = *(const uint4*)gk2; kr1 = *(const uint4*)(gk2 + 8);
        vr0 = *(const uint4*)gv2; vr1 = *(const uint4*)(gv2 + 8);
      }

      // ---- S^T for this wave's k32 x q32 ----
      f32x16 st = {};
#pragma unroll
      for (int c = 0; c < 4; c++) {
        s16x8 kf = *(const s16x8*)&Ks[buf][kh * 32 + l31][c * 16 + hi * 8];
        st = mfma32(kf, qf[c], st);
      }

      // ---- sigmoid (+ causal mask only on the diagonal tile) -> pack into Ps ----
      if (kt == nkv - 1) {
        int qi = q0 + qs * 32 + l31;
        int kbase = kt * 64 + kh * 32 + 4 * hi;
#pragma unroll
        for (int g = 0; g < 4; g++) {
          u16 pk[4];
#pragma unroll
          for (int i = 0; i < 4; i++) {
            float s = st[4 * g + i];
            float e = __builtin_amdgcn_exp2f(s * C1 + C2);
            float p = __builtin_amdgcn_rcpf(1.0f + e);
            if (kbase + 8 * g + i > qi) p = 0.0f;
            pk[i] = f2bf_fast(p);
          }
          uint2 pv;
          pv.x = (unsigned)pk[0] | ((unsigned)pk[1] << 16);
          pv.y = (unsigned)pk[2] | ((unsigned)pk[3] << 16);
          *(uint2*)&Ps[w][l31][8 * g + 4 * hi] = pv;
        }
      } else {
#pragma unroll
        for (int g = 0; g < 4; g++) {
          u16 pk[4];
#pragma unroll
          for (int i = 0; i < 4; i++) {
            float s = st[4 * g + i];
            float e = __builtin_amdgcn_exp2f(s * C1 + C2);
            pk[i] = f2bf_fast(__builtin_amdgcn_rcpf(1.0f + e));
          }
          uint2 pv;
          pv.x = (unsigned)pk[0] | ((unsigned)pk[1] << 16);
          pv.y = (unsigned)pk[2] | ((unsigned)pk[3] << 16);
          *(uint2*)&Ps[w][l31][8 * g + 4 * hi] = pv;
        }
      }

      // ---- partial O += P V over this k32 (per-wave Ps: lgkmcnt ordering suffices) ----
      s16x8 pa[2];
#pragma unroll
      for (int kc = 0; kc < 2; kc++)
        pa[kc] = *(const s16x8*)&Ps[w][l31][kc * 16 + hi * 8];
#pragma unroll
      for (int dt = 0; dt < 2; dt++)
#pragma unroll
        for (int kc = 0; kc < 2; kc++) {
          s16x8 vf = *(const s16x8*)&Vs[buf][dt * 32 + l31][kh * 32 + kc * 16 + hi * 8];
          oacc[dt] = mfma32(pa[kc], vf, oacc[dt]);
        }
    }

    // ---- epilogue: reduce the two k-halves via LDS scratch, then store ----
    __syncthreads();  // all K/V reads done; Ks space reusable as Osc
    if (kh == 1) {
#pragma unroll
      for (int dt = 0; dt < 2; dt++)
#pragma unroll
        for (int reg = 0; reg < 16; reg++) {
          int ql = (reg & 3) + 8 * (reg >> 2) + 4 * hi;
          Osc[(qs * 32 + ql) * 66 + dt * 32 + l31] = oacc[dt][reg];
        }
    }
    __syncthreads();
    if (kh == 0) {
#pragma unroll
      for (int dt = 0; dt < 2; dt++)
#pragma unroll
        for (int reg = 0; reg < 16; reg++) {
          int ql = (reg & 3) + 8 * (reg >> 2) + 4 * hi;
          float v = oacc[dt][reg] + Osc[(qs * 32 + ql) * 66 + dt * 32 + l31];
          int row = q0 + qs * 32 + ql;
          int col = h * 64 + dt * 32 + l31;
          size_t idx = (size_t)(b * SQ_ + row) * D_ + col;
          out0[idx] = v;
          atv_bf[idx] = f2bf(v);
        }
    }
    __syncthreads();  // scratch/LDS free before next half restages
  }
}

extern "C" void kernel_launch(void* const* d_in, const int* in_sizes, int n_in,
                              void* d_out, int out_size, void* d_ws, size_t ws_size,
                              hipStream_t stream) {
  const float* q      = (const float*)d_in[0];
  const float* kv     = (const float*)d_in[1];
  const float* Wq     = (const float*)d_in[2];
  const float* Wkv    = (const float*)d_in[3];
  const float* vgamma = (const float*)d_in[4];
  const float* vbeta  = (const float*)d_in[5];
  const float* Wproj  = (const float*)d_in[6];
  float* out0 = (float*)d_out;
  float* out1 = out0 + (size_t)B_ * SQ_ * D_;

  char* p = (char*)d_ws;
  u16* q_bf  = (u16*)p; p += (size_t)B_ * SQ_ * D_ * 2;
  u16* kv_bf = (u16*)p; p += (size_t)B_ * SKV_ * D_ * 2;
  u16* WqT   = (u16*)p; p += (size_t)D_ * D_ * 2;
  u16* WkvT  = (u16*)p; p += (size_t)2 * D_ * D_ * 2;
  u16* WprT  = (u16*)p; p += (size_t)D_ * D_ * 2;
  u16* qh    = (u16*)p; p += (size_t)B_ * SQ_ * D_ * 2;
  u16* kvh   = (u16*)p; p += (size_t)B_ * SKV_ * 2 * D_ * 2;
  u16* vt    = (u16*)p; p += (size_t)B_ * H_ * HD_ * SKV_ * 2;
  u16* atv   = (u16*)p; p += (size_t)B_ * SQ_ * D_ * 2;

  prep_kernel<<<dim3(12288), 256, 0, stream>>>(q, q_bf, kv, kv_bf, Wq, WqT, Wkv, WkvT, Wproj, WprT);

  gemm_qkv<<<dim3(24, 32), 256, 0, stream>>>(q_bf, WqT, qh, kv_bf, WkvT, kvh);

  ln_vt_kernel<<<dim3((B_ * H_ * SKV_) / 64), 256, 0, stream>>>(kvh, vgamma, vbeta, vt);

  attn_kernel<<<dim3(32, 16), 256, 0, stream>>>(qh, kvh, vt, out0, atv);

  gemm_proj<<<dim3(8, 64), 256, 0, stream>>>(atv, WprT, out1);
}

// Round 7
// 201.885 us; speedup vs baseline: 2.1616x; 1.0129x over previous
//
#include <hip/hip_runtime.h>
#include <hip/hip_bf16.h>

#define B_ 2
#define SQ_ 2048
#define SKV_ 2048
#define D_ 1024
#define H_ 16
#define HD_ 64

typedef unsigned short u16;
typedef float f32x4 __attribute__((ext_vector_type(4)));
typedef float f32x16 __attribute__((ext_vector_type(16)));
typedef short s16x8 __attribute__((ext_vector_type(8)));

__device__ __forceinline__ u16 f2bf(float f) {
  union { float f; unsigned u; } v; v.f = f;
  return (u16)((v.u + 0x7FFFu + ((v.u >> 16) & 1u)) >> 16);
}
__device__ __forceinline__ float bf2f(u16 h) {
  union { unsigned u; float f; } v; v.u = ((unsigned)h) << 16;
  return v.f;
}
// pack bf16(s1)<<16 | bf16(s0), round-half-up: 2 adds + 1 v_perm
__device__ __forceinline__ unsigned pack2bf(float s0, float s1) {
  union { float f; unsigned u; } a, b; a.f = s0; b.f = s1;
  return __builtin_amdgcn_perm(b.u + 0x8000u, a.u + 0x8000u, 0x07060302u);
}
__device__ __forceinline__ f32x4 mfma16(s16x8 a, s16x8 b, f32x4 c) {
  return __builtin_amdgcn_mfma_f32_16x16x32_bf16(a, b, c, 0, 0, 0);
}
__device__ __forceinline__ f32x16 mfma32(s16x8 a, s16x8 b, f32x16 c) {
  return __builtin_amdgcn_mfma_f32_32x32x16_bf16(a, b, c, 0, 0, 0);
}
// async 16B/lane global -> LDS (dest = wave-uniform base + lane*16)
__device__ __forceinline__ void async16(const u16* g, u16* l) {
  __builtin_amdgcn_global_load_lds(
      (const __attribute__((address_space(1))) unsigned int*)g,
      (__attribute__((address_space(3))) unsigned int*)l, 16, 0, 0);
}

// ---------------- fused prep: cast q, cast kv, transpose 3 weights ----------------
__device__ __forceinline__ void tr_tile(const float* __restrict__ in, u16* __restrict__ out,
                                        int R, int C, int cx, int ry, int t) {
  __shared__ u16 tile[32][33];
  int tx = t & 31, ty = t >> 5;
  int c0 = cx * 32, r0 = ry * 32;
#pragma unroll
  for (int i = 0; i < 4; i++)
    tile[ty + i * 8][tx] = f2bf(in[(size_t)(r0 + ty + i * 8) * C + c0 + tx]);
  __syncthreads();
#pragma unroll
  for (int i = 0; i < 4; i++)
    out[(size_t)(c0 + ty + i * 8) * R + r0 + tx] = tile[tx][ty + i * 8];
}

__device__ __forceinline__ void cast4(const float* __restrict__ in, u16* __restrict__ out,
                                      int i) {
  float4 f = *(const float4*)(in + i);
  ushort4 o;
  o.x = f2bf(f.x); o.y = f2bf(f.y); o.z = f2bf(f.z); o.w = f2bf(f.w);
  *(ushort4*)(out + i) = o;
}

__global__ __launch_bounds__(256) void prep_kernel(
    const float* __restrict__ q, u16* __restrict__ q_bf,
    const float* __restrict__ kv, u16* __restrict__ kv_bf,
    const float* __restrict__ Wq, u16* __restrict__ WqT,
    const float* __restrict__ Wkv, u16* __restrict__ WkvT,
    const float* __restrict__ Wproj, u16* __restrict__ WprT) {
  int bid = blockIdx.x, t = threadIdx.x;
  if (bid < 4096) {
    cast4(q, q_bf, bid * 1024 + t * 4);
  } else if (bid < 8192) {
    cast4(kv, kv_bf, (bid - 4096) * 1024 + t * 4);
  } else if (bid < 9216) {
    int b2 = bid - 8192;
    tr_tile(Wq, WqT, 1024, 1024, b2 & 31, b2 >> 5, t);
  } else if (bid < 11264) {
    int b2 = bid - 9216;
    tr_tile(Wkv, WkvT, 1024, 2048, b2 & 63, b2 >> 6, t);
  } else {
    int b2 = bid - 11264;
    tr_tile(Wproj, WprT, 1024, 1024, b2 & 31, b2 >> 5, t);
  }
}

// ------- m97-style GEMM body: C(BMxBN) = A(BM x K) * BT(BN x K)^T -------
template <int BM, int BN, bool OUT_BF16>
__device__ __forceinline__ void gemm_body(const u16* __restrict__ A,
                                          const u16* __restrict__ BT,
                                          void* __restrict__ Cout,
                                          int m0, int n0, int N, int K) {
  __shared__ __attribute__((aligned(16))) u16 As[BM][32];
  __shared__ __attribute__((aligned(16))) u16 Bs[BN][32];
  constexpr int AM = BM / 32, AN = BN / 32;
  int t = threadIdx.x, w = t >> 6, lane = t & 63;
  int l16 = lane & 15, quad = lane >> 4;
  int mw = (w >> 1) * (BM / 2), nw = (w & 1) * (BN / 2);
  int grow = w * 16 + (lane >> 2);
  int gcol = (lane & 3) * 8;

  f32x4 acc[AM][AN] = {};

  for (int kt = 0; kt < K; kt += 32) {
    __syncthreads();
#pragma unroll
    for (int j = 0; j < BM / 64; j++)
      async16(A + (size_t)(m0 + j * 64 + grow) * K + kt + gcol, &As[j * 64 + w * 16][0]);
#pragma unroll
    for (int j = 0; j < BN / 64; j++)
      async16(BT + (size_t)(n0 + j * 64 + grow) * K + kt + gcol, &Bs[j * 64 + w * 16][0]);
    __syncthreads();
    s16x8 af[AM], bf[AN];
#pragma unroll
    for (int i = 0; i < AM; i++) af[i] = *(const s16x8*)&As[mw + i * 16 + l16][quad * 8];
#pragma unroll
    for (int j = 0; j < AN; j++) bf[j] = *(const s16x8*)&Bs[nw + j * 16 + l16][quad * 8];
#pragma unroll
    for (int i = 0; i < AM; i++)
#pragma unroll
      for (int j = 0; j < AN; j++)
        acc[i][j] = mfma16(af[i], bf[j], acc[i][j]);
  }

#pragma unroll
  for (int i = 0; i < AM; i++)
#pragma unroll
    for (int j = 0; j < AN; j++) {
      int col = n0 + nw + j * 16 + l16;
#pragma unroll
      for (int r = 0; r < 4; r++) {
        int row = m0 + mw + i * 16 + quad * 4 + r;
        float v = acc[i][j][r];
        if (OUT_BF16)
          ((u16*)Cout)[(size_t)row * N + col] = f2bf(v);
        else
          ((float*)Cout)[(size_t)row * N + col] = v;
      }
    }
}

__global__ __launch_bounds__(256, 3) void gemm_qkv(const u16* __restrict__ q_bf,
                                                   const u16* __restrict__ WqT,
                                                   u16* __restrict__ qh,
                                                   const u16* __restrict__ kv_bf,
                                                   const u16* __restrict__ WkvT,
                                                   u16* __restrict__ kvh) {
  int bx = blockIdx.x;
  if (bx < 8)
    gemm_body<128, 128, true>(q_bf, WqT, qh, blockIdx.y * 128, bx * 128, D_, D_);
  else
    gemm_body<128, 128, true>(kv_bf, WkvT, kvh, blockIdx.y * 128, (bx - 8) * 128, 2 * D_, D_);
}

__global__ __launch_bounds__(256, 3) void gemm_proj(const u16* __restrict__ A,
                                                    const u16* __restrict__ BT,
                                                    float* __restrict__ C) {
  gemm_body<64, 128, false>(A, BT, C, blockIdx.y * 64, blockIdx.x * 128, D_, D_);
}

// ---------------- LayerNorm of v + transpose into vt[b,h,d,s] ----------------
__global__ __launch_bounds__(256) void ln_vt_kernel(const u16* __restrict__ kvh,
                                                    const float* __restrict__ gamma,
                                                    const float* __restrict__ beta,
                                                    u16* __restrict__ vt) {
  __shared__ __attribute__((aligned(16))) u16 tile[64][72];  // [d][s]
  int bid = blockIdx.x;
  int stile = bid & 31;
  int h = (bid >> 5) & 15;
  int b = bid >> 9;
  int wave = threadIdx.x >> 6, lane = threadIdx.x & 63;
  float g = gamma[lane], be = beta[lane];
#pragma unroll 4
  for (int i = 0; i < 16; i++) {
    int s = stile * 64 + wave * 16 + i;
    float x = bf2f(kvh[(size_t)(b * SKV_ + s) * 2048 + 1024 + h * 64 + lane]);
    float sum = x;
#pragma unroll
    for (int off = 32; off; off >>= 1) sum += __shfl_xor(sum, off, 64);
    float mu = sum * (1.0f / 64.0f);
    float dx = x - mu;
    float s2 = dx * dx;
#pragma unroll
    for (int off = 32; off; off >>= 1) s2 += __shfl_xor(s2, off, 64);
    float inv = rsqrtf(s2 * (1.0f / 64.0f) + 1e-5f);
    tile[lane][wave * 16 + i] = f2bf(dx * inv * g + be);
  }
  __syncthreads();
  int d = threadIdx.x >> 2, sc = (threadIdx.x & 3) * 16;
  size_t orow = ((size_t)(b * H_ + h) * 64 + d) * SKV_ + stile * 64 + sc;
  uint4 v0 = *(const uint4*)&tile[d][sc];
  uint4 v1 = *(const uint4*)&tile[d][sc + 8];
  *(uint4*)(vt + orow) = v0;
  *(uint4*)(vt + orow + 8) = v1;
}

// ---------------- attention: q64 tiles, grid (32 bh x 32 qt) = 1024 blocks ----------------
// No pairing (staging traffic is identical either way; measured R6). y -> qt DESCENDING so
// the x-major dispatch order emits the longest blocks first (LPT schedule; max block 32
// iters << 66 iters/CU). LDS 44 KB + 88 VGPR -> 3 resident blocks/CU (grid was the cap).
// Wave w: qs = w&1 (q32 strip), kh = w>>1 (k32 half). S^T = mfma32(A=K, B=Q) -> sigmoid
// (v_perm bf16 pack) -> Ps[q][k] (PV A-operand layout) -> partial O over k-half; epilogue
// reduces halves via LDS scratch. Strides 68/36/66: measured conflict-free family.
__global__ __launch_bounds__(256, 2) void attn_kernel(const u16* __restrict__ qh,
                                                      const u16* __restrict__ kvh,
                                                      const u16* __restrict__ vt,
                                                      float* __restrict__ out0,
                                                      u16* __restrict__ atv_bf) {
  __shared__ __attribute__((aligned(16))) u16 Ks[2][64][68];  // [buf][kv][d] 17408 B
  __shared__ __attribute__((aligned(16))) u16 Vs[2][64][68];  // [buf][d][kv] 17408 B
  __shared__ __attribute__((aligned(16))) u16 Ps[4][32][36];  // [wave][q][k32] 9216 B

  int bh = blockIdx.x;          // 0..31
  int qt = 31 - blockIdx.y;     // descending work size
  int h = bh & 15, b = bh >> 4;
  int t = threadIdx.x;
  int w = t >> 6, lane = t & 63;
  int l31 = lane & 31, hi = lane >> 5;
  int qs = w & 1, kh = w >> 1;
  int srow = t >> 2;            // staging row 0..63
  int scol = (t & 3) * 16;      // staging col (elements)

  const float C1 = -0.18033688011f;  // -0.125 * log2(e)
  const float C2 = 11.5415603272f;   // 8 * log2(e)

  const u16* gkb = kvh + ((size_t)(b * SKV_) + srow) * 2048 + h * 64 + scol;
  const u16* gvb = vt + ((size_t)((b * H_ + h) * 64 + srow)) * 2048 + scol;
  float* Osc = (float*)&Ks[0][0][0];  // epilogue scratch alias: 64*66*4 = 16896 <= 17408

  int q0 = qt * 64;
  int nkv = qt + 1;

  // Q fragments (B-operand): lane q = q0 + qs*32 + l31, k_dim d = c*16 + hi*8 + j
  s16x8 qf[4];
  {
    const u16* qp = qh + (size_t)(b * SQ_ + q0 + qs * 32 + l31) * D_ + h * 64 + hi * 8;
#pragma unroll
    for (int c = 0; c < 4; c++) qf[c] = *(const s16x8*)(qp + c * 16);
  }

  f32x16 oacc[2] = {};  // partial O (this wave's k-half): [dt] 32q x 32d

  uint4 kr0 = *(const uint4*)gkb, kr1 = *(const uint4*)(gkb + 8);
  uint4 vr0 = *(const uint4*)gvb, vr1 = *(const uint4*)(gvb + 8);

  for (int kt = 0; kt < nkv; kt++) {
    int buf = kt & 1;
    *(uint4*)&Ks[buf][srow][scol] = kr0; *(uint4*)&Ks[buf][srow][scol + 8] = kr1;
    *(uint4*)&Vs[buf][srow][scol] = vr0; *(uint4*)&Vs[buf][srow][scol + 8] = vr1;
    __syncthreads();  // also separates kt-2 reads from this kt's writes (dbuf)
    if (kt + 1 < nkv) {
      const u16* gk2 = gkb + (size_t)(kt + 1) * 64 * 2048;
      const u16* gv2 = gvb + (size_t)(kt + 1) * 64;
      kr0 = *(const uint4*)gk2; kr1 = *(const uint4*)(gk2 + 8);
      vr0 = *(const uint4*)gv2; vr1 = *(const uint4*)(gv2 + 8);
    }

    // ---- S^T for this wave's k32 x q32 ----
    f32x16 st = {};
#pragma unroll
    for (int c = 0; c < 4; c++) {
      s16x8 kf = *(const s16x8*)&Ks[buf][kh * 32 + l31][c * 16 + hi * 8];
      st = mfma32(kf, qf[c], st);
    }

    // ---- sigmoid (+ causal mask only on the diagonal tile) -> pack into Ps ----
    if (kt == nkv - 1) {
      int qi = q0 + qs * 32 + l31;
      int kbase = kt * 64 + kh * 32 + 4 * hi;
#pragma unroll
      for (int g = 0; g < 4; g++) {
        float pv4[4];
#pragma unroll
        for (int i = 0; i < 4; i++) {
          float s = st[4 * g + i];
          float e = __builtin_amdgcn_exp2f(s * C1 + C2);
          float p = __builtin_amdgcn_rcpf(1.0f + e);
          pv4[i] = (kbase + 8 * g + i > qi) ? 0.0f : p;
        }
        uint2 pv;
        pv.x = pack2bf(pv4[0], pv4[1]);
        pv.y = pack2bf(pv4[2], pv4[3]);
        *(uint2*)&Ps[w][l31][8 * g + 4 * hi] = pv;
      }
    } else {
#pragma unroll
      for (int g = 0; g < 4; g++) {
        float pv4[4];
#pragma unroll
        for (int i = 0; i < 4; i++) {
          float s = st[4 * g + i];
          float e = __builtin_amdgcn_exp2f(s * C1 + C2);
          pv4[i] = __builtin_amdgcn_rcpf(1.0f + e);
        }
        uint2 pv;
        pv.x = pack2bf(pv4[0], pv4[1]);
        pv.y = pack2bf(pv4[2], pv4[3]);
        *(uint2*)&Ps[w][l31][8 * g + 4 * hi] = pv;
      }
    }

    // ---- partial O += P V over this k32 (per-wave Ps: lgkmcnt ordering suffices) ----
    s16x8 pa[2];
#pragma unroll
    for (int kc = 0; kc < 2; kc++)
      pa[kc] = *(const s16x8*)&Ps[w][l31][kc * 16 + hi * 8];
#pragma unroll
    for (int dt = 0; dt < 2; dt++)
#pragma unroll
      for (int kc = 0; kc < 2; kc++) {
        s16x8 vf = *(const s16x8*)&Vs[buf][dt * 32 + l31][kh * 32 + kc * 16 + hi * 8];
        oacc[dt] = mfma32(pa[kc], vf, oacc[dt]);
      }
  }

  // ---- epilogue: reduce the two k-halves via LDS scratch, then store ----
  __syncthreads();  // all K/V reads done; Ks space reusable as Osc
  if (kh == 1) {
#pragma unroll
    for (int dt = 0; dt < 2; dt++)
#pragma unroll
      for (int reg = 0; reg < 16; reg++) {
        int ql = (reg & 3) + 8 * (reg >> 2) + 4 * hi;
        Osc[(qs * 32 + ql) * 66 + dt * 32 + l31] = oacc[dt][reg];
      }
  }
  __syncthreads();
  if (kh == 0) {
#pragma unroll
    for (int dt = 0; dt < 2; dt++)
#pragma unroll
      for (int reg = 0; reg < 16; reg++) {
        int ql = (reg & 3) + 8 * (reg >> 2) + 4 * hi;
        float v = oacc[dt][reg] + Osc[(qs * 32 + ql) * 66 + dt * 32 + l31];
        int row = q0 + qs * 32 + ql;
        int col = h * 64 + dt * 32 + l31;
        size_t idx = (size_t)(b * SQ_ + row) * D_ + col;
        out0[idx] = v;
        atv_bf[idx] = f2bf(v);
      }
  }
}

extern "C" void kernel_launch(void* const* d_in, const int* in_sizes, int n_in,
                              void* d_out, int out_size, void* d_ws, size_t ws_size,
                              hipStream_t stream) {
  const float* q      = (const float*)d_in[0];
  const float* kv     = (const float*)d_in[1];
  const float* Wq     = (const float*)d_in[2];
  const float* Wkv    = (const float*)d_in[3];
  const float* vgamma = (const float*)d_in[4];
  const float* vbeta  = (const float*)d_in[5];
  const float* Wproj  = (const float*)d_in[6];
  float* out0 = (float*)d_out;
  float* out1 = out0 + (size_t)B_ * SQ_ * D_;

  char* p = (char*)d_ws;
  u16* q_bf  = (u16*)p; p += (size_t)B_ * SQ_ * D_ * 2;
  u16* kv_bf = (u16*)p; p += (size_t)B_ * SKV_ * D_ * 2;
  u16* WqT   = (u16*)p; p += (size_t)D_ * D_ * 2;
  u16* WkvT  = (u16*)p; p += (size_t)2 * D_ * D_ * 2;
  u16* WprT  = (u16*)p; p += (size_t)D_ * D_ * 2;
  u16* qh    = (u16*)p; p += (size_t)B_ * SQ_ * D_ * 2;
  u16* kvh   = (u16*)p; p += (size_t)B_ * SKV_ * 2 * D_ * 2;
  u16* vt    = (u16*)p; p += (size_t)B_ * H_ * HD_ * SKV_ * 2;
  u16* atv   = (u16*)p; p += (size_t)B_ * SQ_ * D_ * 2;

  prep_kernel<<<dim3(12288), 256, 0, stream>>>(q, q_bf, kv, kv_bf, Wq, WqT, Wkv, WkvT, Wproj, WprT);

  gemm_qkv<<<dim3(24, 32), 256, 0, stream>>>(q_bf, WqT, qh, kv_bf, WkvT, kvh);

  ln_vt_kernel<<<dim3((B_ * H_ * SKV_) / 64), 256, 0, stream>>>(kvh, vgamma, vbeta, vt);

  attn_kernel<<<dim3(32, 32), 256, 0, stream>>>(qh, kvh, vt, out0, atv);

  gemm_proj<<<dim3(8, 64), 256, 0, stream>>>(atv, WprT, out1);
}